// Round 4
// baseline (757.818 us; speedup 1.0000x reference)
//
#include <hip/hip_runtime.h>
#include <hip/hip_bf16.h>
#include <math.h>

#define NB 2
#define NC 256
#define NZ 128
#define NHEADS 8
#define HDIM 64
#define HHID 512
#define EPSF 1e-5f
#define TWO_PI_F 6.283185307179586f

typedef __attribute__((ext_vector_type(8))) short bf16x8;
typedef __attribute__((ext_vector_type(4))) float f32x4;
typedef unsigned short ushort_t;

__device__ __forceinline__ float gelu_f(float x){
  const float u = 0.7978845608028654f * (x + 0.044715f * x * x * x);
  const float t = 1.0f - 2.0f / (__expf(2.0f * u) + 1.0f);  // tanh(u)
  return 0.5f * x * (1.0f + t);
}

__device__ __forceinline__ ushort_t f2bf(float x){
  unsigned int u = __float_as_uint(x);
  unsigned int r = ((u >> 16) & 1u) + 0x7fffu;   // round-to-nearest-even
  return (ushort_t)((u + r) >> 16);
}

// ---------------- K0: pack weights to bf16 MFMA-fragment order ----------------
// B-frag: idx=((s*T + t)*64 + L)*8 + j  <->  W[k=s*32+8*(L>>4)+j][n=16*t+(L&15)]
__global__ __launch_bounds__(256) void eca_pack(
    const float* __restrict__ mW1, const float* __restrict__ mW2, const float* __restrict__ vW2,
    const float* __restrict__ Wve, const float* __restrict__ vW1,
    const float* __restrict__ bve, const float* __restrict__ vb1,
    ushort_t* __restrict__ W1p, ushort_t* __restrict__ W2p, ushort_t* __restrict__ vW2p,
    ushort_t* __restrict__ WveFp, float* __restrict__ bveF)
{
  if (blockIdx.x == 1024){
    // fused front weight: WveF = Wve @ vW1 (64x64), bveF = bve@vW1 + vb1
    __shared__ float s_wf[64][64];
    const int tid = threadIdx.x;
    const int m = tid >> 2, iq = tid & 3;
    float accv[16];
    #pragma unroll
    for (int ii = 0; ii < 16; ++ii) accv[ii] = 0.f;
    for (int k = 0; k < 64; ++k){
      const float wv = Wve[m * 64 + k];
      const float4* vr = (const float4*)(vW1 + k * 64 + iq * 16);
      float t4[16];
      *(float4*)&t4[0] = vr[0]; *(float4*)&t4[4] = vr[1];
      *(float4*)&t4[8] = vr[2]; *(float4*)&t4[12] = vr[3];
      #pragma unroll
      for (int ii = 0; ii < 16; ++ii) accv[ii] += wv * t4[ii];
    }
    #pragma unroll
    for (int ii = 0; ii < 16; ++ii) s_wf[m][iq * 16 + ii] = accv[ii];
    if (tid < 64){
      float acc = vb1[tid];
      for (int k = 0; k < 64; ++k) acc += bve[k] * vW1[k * 64 + tid];
      bveF[tid] = acc;
    }
    __syncthreads();
    for (int e = tid; e < 4096; e += 256){
      const int j = e & 7, L = (e >> 3) & 63, t = (e >> 9) & 3, s = e >> 11;
      const int k = s * 32 + ((L >> 4) << 3) + j;
      const int n = (t << 4) + (L & 15);
      WveFp[e] = f2bf(s_wf[k][n]);
    }
    return;
  }
  const int i = blockIdx.x * 256 + threadIdx.x;
  {
    const int j = i & 7, L = (i >> 3) & 63, t = (i >> 9) & 31, s = i >> 14;
    const int k = s * 32 + ((L >> 4) << 3) + j;
    const int n = (t << 4) + (L & 15);
    W1p[i] = f2bf(mW1[k * 512 + n]);
    W2p[i] = f2bf(mW2[k * 512 + n]);
  }
  if (i < 65536){
    const int j = i & 7, L = (i >> 3) & 63, gb = (i >> 9) & 1, tp = (i >> 10) & 31, s = i >> 15;
    const int k = s * 32 + ((L >> 4) << 3) + j;
    const int n = (tp << 4) + (L & 15) + gb * 512;
    vW2p[i] = f2bf(vW2[k * 1024 + n]);
  }
}

// ---------------- K1: per-(b,z) latent precompute + KqF fold ----------------
__global__ __launch_bounds__(256) void eca_prep(
    const float* __restrict__ a, const float* __restrict__ Wk, const float* __restrict__ bk,
    const float* __restrict__ Wv, const float* __restrict__ bv,
    const float* __restrict__ Wq, const float* __restrict__ bq,
    const float* __restrict__ Wqe, const float* __restrict__ bqe,
    float* __restrict__ v0g, float* __restrict__ kqf, float* __restrict__ bqkg)
{
  const int bz = blockIdx.x;
  const int tid = threadIdx.x;
  __shared__ float s_a[64];
  __shared__ float s_k[512];
  __shared__ float s_kq[512];
  if (tid < 64) s_a[tid] = a[bz * 64 + tid];
  __syncthreads();
  #pragma unroll
  for (int jo = 0; jo < 2; ++jo){
    const int j = tid + jo * 256;
    float accK = bk[j], accV = bv[j];
    for (int i = 0; i < 64; ++i){
      const float av = s_a[i];
      accK += av * Wk[i * 512 + j];
      accV += av * Wv[i * 512 + j];
    }
    s_k[j] = accK;
    v0g[(size_t)bz * 512 + j] = accV;
  }
  __syncthreads();
  // Kq[h,i] = sum_j Wq[i, h*64+j] * k[h*64+j]
  #pragma unroll
  for (int io = 0; io < 2; ++io){
    const int idx = tid + io * 256;
    const int h = idx >> 6, i = idx & 63;
    float acc = 0.f;
    for (int j = 0; j < 64; ++j)
      acc += Wq[i * 512 + h * 64 + j] * s_k[h * 64 + j];
    s_kq[idx] = acc;
  }
  __syncthreads();
  // KqF[m,h] = sum_i Wqe[m,i] * Kq[h,i]; layout kqf[bz*512 + (m>>4)*128 + h*16 + (m&15)]
  #pragma unroll
  for (int io = 0; io < 2; ++io){
    const int idx = tid + io * 256;
    const int m = idx >> 3, h = idx & 7;
    float acc = 0.f;
    for (int i = 0; i < 64; ++i) acc += Wqe[m * 64 + i] * s_kq[h * 64 + i];
    kqf[(size_t)bz * 512 + (m >> 4) * 128 + h * 16 + (m & 15)] = acc;
  }
  if (tid < 8){
    float acc = 0.f;
    for (int j = 0; j < 64; ++j) acc += bq[tid * 64 + j] * s_k[tid * 64 + j];
    for (int i = 0; i < 64; ++i) acc += bqe[i] * s_kq[tid * 64 + i];
    bqkg[bz * 8 + tid] = acc;
  }
}

// ---------------- K3: fused per-(b,c), two 64-z passes, 78KB LDS ----------------
__global__ __launch_bounds__(512, 4) void eca_main(
    const float* __restrict__ inputs, const float* __restrict__ p,
    const float* __restrict__ Bq, const float* __restrict__ Bv,
    const float* __restrict__ vg, const float* __restrict__ vbn,
    const float* __restrict__ vb2,
    const float* __restrict__ mb1, const float* __restrict__ mg, const float* __restrict__ mbn,
    const float* __restrict__ mb2,
    const float* __restrict__ v0g, const float* __restrict__ kqf, const float* __restrict__ bqkg,
    const ushort_t* __restrict__ W1p, const ushort_t* __restrict__ W2p, const ushort_t* __restrict__ vW2p,
    const ushort_t* __restrict__ WveFp, const float* __restrict__ bveF,
    float* __restrict__ yout)
{
  const int bc = blockIdx.x;
  const int b = bc >> 8;
  const int tid = threadIdx.x;
  const int w = tid >> 6, L = tid & 63;
  const int al = L & 15, g = L >> 4;
  const int bz0 = b * NZ;

  __shared__ __align__(16) ushort_t s_A[16 * 4 * 64 * 8];   // 64KB A-frags (64 z x 512)
  __shared__ __align__(16) ushort_t s_HN[2 * 4 * 64 * 8];   // 8KB hn frags (64 z x 64)
  __shared__ float s_u[1024];                                // union: logits[8][128] / ln64 / ln512
  __shared__ float s_mu[64], s_rs[64];
  __shared__ float s_qpt[3];

  if (tid < 3) s_qpt[tid] = inputs[bc * 3 + tid];
  __syncthreads();

  // ---------- logits: thread (z = tid>>2, q = tid&3); lg[h] = sum_m f_q[m]*KqF[z,h,m] ----------
  {
    const int z = tid >> 2, q = tid & 3;
    const float iv0 = s_qpt[0] - p[(bz0 + z) * 3 + 0];
    const float iv1 = s_qpt[1] - p[(bz0 + z) * 3 + 1];
    const float iv2 = s_qpt[2] - p[(bz0 + z) * 3 + 2];
    float tr[16];
    #pragma unroll
    for (int mi = 0; mi < 16; ++mi){
      const int mb = (q & 1) * 16 + mi;
      const float pr = TWO_PI_F * (iv0 * Bq[mb] + iv1 * Bq[32 + mb] + iv2 * Bq[64 + mb]);
      float sn, cn; sincosf(pr, &sn, &cn);
      tr[mi] = (q < 2) ? sn : cn;
    }
    const float* kfb = kqf + (size_t)(bz0 + z) * 512 + q * 128;
    float lg[8];
    #pragma unroll
    for (int h = 0; h < 8; ++h){
      const float4 k0 = *(const float4*)(kfb + h * 16);
      const float4 k1 = *(const float4*)(kfb + h * 16 + 4);
      const float4 k2 = *(const float4*)(kfb + h * 16 + 8);
      const float4 k3 = *(const float4*)(kfb + h * 16 + 12);
      lg[h] = tr[0]*k0.x + tr[1]*k0.y + tr[2]*k0.z + tr[3]*k0.w
            + tr[4]*k1.x + tr[5]*k1.y + tr[6]*k1.z + tr[7]*k1.w
            + tr[8]*k2.x + tr[9]*k2.y + tr[10]*k2.z + tr[11]*k2.w
            + tr[12]*k3.x + tr[13]*k3.y + tr[14]*k3.z + tr[15]*k3.w;
    }
    #pragma unroll
    for (int h = 0; h < 8; ++h){
      lg[h] += __shfl_xor(lg[h], 1);
      lg[h] += __shfl_xor(lg[h], 2);
    }
    const int h0 = q * 2;
    s_u[h0 * 128 + z]       = (lg[h0]     + bqkg[(bz0 + z) * 8 + h0])     * 0.125f;
    s_u[(h0 + 1) * 128 + z] = (lg[h0 + 1] + bqkg[(bz0 + z) * 8 + h0 + 1]) * 0.125f;
  }
  __syncthreads();

  // ---------- softmax (head w per wave) -> att in registers ----------
  float att0, att1;
  {
    const float x0 = s_u[w * 128 + L], x1 = s_u[w * 128 + L + 64];
    float mx = fmaxf(x0, x1);
    #pragma unroll
    for (int off = 32; off; off >>= 1) mx = fmaxf(mx, __shfl_xor(mx, off));
    const float e0 = __expf(x0 - mx), e1 = __expf(x1 - mx);
    float sm = e0 + e1;
    #pragma unroll
    for (int off = 32; off; off >>= 1) sm += __shfl_xor(sm, off);
    const float inv = 1.f / sm;
    att0 = e0 * inv; att1 = e1 * inv;
  }

  // per-thread constants
  const int rtf = w & 3, ch2 = w >> 2;          // front roles
  float vgr[2], vbnr[2], bver[2];
  #pragma unroll
  for (int ct = 0; ct < 2; ++ct){
    const int n = ch2 * 32 + ct * 16 + al;
    vgr[ct] = vg[n]; vbnr[ct] = vbn[n]; bver[ct] = bveF[n];
  }
  float mb1r[4], mgr[4], mbnr[4];
  #pragma unroll
  for (int ct = 0; ct < 4; ++ct){
    const int n = w * 64 + ct * 16 + al;
    mb1r[ct] = mb1[n]; mgr[ct] = mg[n]; mbnr[ct] = mbn[n];
  }
  float yv[4] = {0.f, 0.f, 0.f, 0.f};

  for (int pass = 0; pass < 2; ++pass){
    const int zp = pass * 64;
    __syncthreads();                                   // protect s_u / s_A reuse

    // ---------- front: hn = LN64(gelu(f @ WveF + bveF)); A-frags in registers ----------
    {
      const int zz = bz0 + zp + rtf * 16 + al;
      const float iv0 = s_qpt[0] - p[zz * 3 + 0];
      const float iv1 = s_qpt[1] - p[zz * 3 + 1];
      const float iv2 = s_qpt[2] - p[zz * 3 + 2];
      bf16x8 fa0, fa1;
      #pragma unroll
      for (int j = 0; j < 8; ++j){
        const int m = g * 8 + j;
        const float pr = TWO_PI_F * (iv0 * Bv[m] + iv1 * Bv[32 + m] + iv2 * Bv[64 + m]);
        float sn, cn; sincosf(pr, &sn, &cn);
        fa0[j] = (short)f2bf(sn);
        fa1[j] = (short)f2bf(cn);
      }
      f32x4 accf[2] = {{0,0,0,0},{0,0,0,0}};
      #pragma unroll
      for (int ct = 0; ct < 2; ++ct){
        const int t = ch2 * 2 + ct;
        const bf16x8 b0 = *(const bf16x8*)(WveFp + ((0 * 4 + t) * 64 + L) * 8);
        const bf16x8 b1 = *(const bf16x8*)(WveFp + ((1 * 4 + t) * 64 + L) * 8);
        accf[ct] = __builtin_amdgcn_mfma_f32_16x16x32_bf16(fa0, b0, accf[ct], 0, 0, 0);
        accf[ct] = __builtin_amdgcn_mfma_f32_16x16x32_bf16(fa1, b1, accf[ct], 0, 0, 0);
      }
      float h1v[2][4];
      #pragma unroll
      for (int r = 0; r < 4; ++r){
        float sv = 0.f, qv = 0.f;
        #pragma unroll
        for (int ct = 0; ct < 2; ++ct){
          const float v = gelu_f(accf[ct][r] + bver[ct]);
          h1v[ct][r] = v; sv += v; qv += v * v;
        }
        sv += __shfl_xor(sv, 1); sv += __shfl_xor(sv, 2);
        sv += __shfl_xor(sv, 4); sv += __shfl_xor(sv, 8);
        qv += __shfl_xor(qv, 1); qv += __shfl_xor(qv, 2);
        qv += __shfl_xor(qv, 4); qv += __shfl_xor(qv, 8);
        if (al == 0){
          const int row = rtf * 16 + 4 * g + r;
          s_u[row * 4 + ch2 * 2 + 0] = sv;
          s_u[row * 4 + ch2 * 2 + 1] = qv;
        }
      }
      __syncthreads();
      #pragma unroll
      for (int r = 0; r < 4; ++r){
        const int row = rtf * 16 + 4 * g + r;
        const float sv = s_u[row * 4 + 0] + s_u[row * 4 + 2];
        const float qv = s_u[row * 4 + 1] + s_u[row * 4 + 3];
        const float mu = sv * (1.f / 64.f);
        const float rs = rsqrtf(qv * (1.f / 64.f) - mu * mu + EPSF);
        #pragma unroll
        for (int ct = 0; ct < 2; ++ct){
          const int n = ch2 * 32 + ct * 16 + al;
          const float val = (h1v[ct][r] - mu) * rs * vgr[ct] + vbnr[ct];
          s_HN[((n >> 5) * 4 + rtf) * 512 + ((4 * g + r) + 16 * ((n >> 3) & 3)) * 8 + (n & 7)] = f2bf(val);
        }
      }
    }
    __syncthreads();

    // ---------- gb MFMA: hn[64x64] @ vW2[64x1024] -> FiLM -> vfilm frags in s_A ----------
    #pragma unroll
    for (int ch = 0; ch < 2; ++ch){
      f32x4 accg[2][4], accb[2][4];
      #pragma unroll
      for (int ti = 0; ti < 2; ++ti)
        #pragma unroll
        for (int rt = 0; rt < 4; ++rt){ accg[ti][rt] = (f32x4){0,0,0,0}; accb[ti][rt] = (f32x4){0,0,0,0}; }
      #pragma unroll
      for (int s = 0; s < 2; ++s){
        bf16x8 afr[4];
        #pragma unroll
        for (int rt = 0; rt < 4; ++rt)
          afr[rt] = *(const bf16x8*)(s_HN + ((s * 4 + rt) * 64 + L) * 8);
        #pragma unroll
        for (int ti = 0; ti < 2; ++ti){
          const int tp = w * 4 + ch * 2 + ti;
          const bf16x8 bg = *(const bf16x8*)(vW2p + (size_t)(((s * 32 + tp) * 2 + 0) * 64 + L) * 8);
          const bf16x8 bb = *(const bf16x8*)(vW2p + (size_t)(((s * 32 + tp) * 2 + 1) * 64 + L) * 8);
          #pragma unroll
          for (int rt = 0; rt < 4; ++rt){
            accg[ti][rt] = __builtin_amdgcn_mfma_f32_16x16x32_bf16(afr[rt], bg, accg[ti][rt], 0, 0, 0);
            accb[ti][rt] = __builtin_amdgcn_mfma_f32_16x16x32_bf16(afr[rt], bb, accb[ti][rt], 0, 0, 0);
          }
        }
      }
      #pragma unroll
      for (int ti = 0; ti < 2; ++ti){
        const int n = (w * 4 + ch * 2 + ti) * 16 + al;
        const float gbias = vb2[n], bbias = vb2[512 + n];
        #pragma unroll
        for (int rt = 0; rt < 4; ++rt){
          #pragma unroll
          for (int r = 0; r < 4; ++r){
            const int zl = rt * 16 + 4 * g + r;
            const float v0v = v0g[(size_t)(bz0 + zp + zl) * 512 + n];
            const float vf = v0v * (1.f + accg[ti][rt][r] + gbias) + (accb[ti][rt][r] + bbias);
            s_A[((n >> 5) * 4 + rt) * 512 + ((4 * g + r) + 16 * ((n >> 3) & 3)) * 8 + (n & 7)] = f2bf(vf);
          }
        }
      }
    }
    __syncthreads();

    // ---------- GEMM1: h2 = vfilm @ mW1; gelu + LN512 -> h2n back to s_A ----------
    f32x4 acc[4][4];
    #pragma unroll
    for (int rt = 0; rt < 4; ++rt)
      #pragma unroll
      for (int ct = 0; ct < 4; ++ct) acc[rt][ct] = (f32x4){0,0,0,0};
    for (int s = 0; s < 16; ++s){
      bf16x8 bw[4];
      #pragma unroll
      for (int ct = 0; ct < 4; ++ct)
        bw[ct] = *(const bf16x8*)(W1p + (size_t)((s * 32 + w * 4 + ct) * 64 + L) * 8);
      #pragma unroll
      for (int rt = 0; rt < 4; ++rt){
        const bf16x8 a = *(const bf16x8*)(s_A + ((s * 4 + rt) * 64 + L) * 8);
        #pragma unroll
        for (int ct = 0; ct < 4; ++ct)
          acc[rt][ct] = __builtin_amdgcn_mfma_f32_16x16x32_bf16(a, bw[ct], acc[rt][ct], 0, 0, 0);
      }
    }
    #pragma unroll
    for (int rt = 0; rt < 4; ++rt){
      #pragma unroll
      for (int r = 0; r < 4; ++r){
        float sv = 0.f, qv = 0.f;
        #pragma unroll
        for (int ct = 0; ct < 4; ++ct){
          const float v = gelu_f(acc[rt][ct][r] + mb1r[ct]);
          acc[rt][ct][r] = v; sv += v; qv += v * v;
        }
        sv += __shfl_xor(sv, 1); sv += __shfl_xor(sv, 2);
        sv += __shfl_xor(sv, 4); sv += __shfl_xor(sv, 8);
        qv += __shfl_xor(qv, 1); qv += __shfl_xor(qv, 2);
        qv += __shfl_xor(qv, 4); qv += __shfl_xor(qv, 8);
        if (al == 0){
          const int zl = rt * 16 + 4 * g + r;
          s_u[zl * 16 + w * 2 + 0] = sv;
          s_u[zl * 16 + w * 2 + 1] = qv;
        }
      }
    }
    __syncthreads();                    // also: all GEMM1 reads of s_A done
    if (tid < 64){
      float sv = 0.f, qv = 0.f;
      #pragma unroll
      for (int ww = 0; ww < 8; ++ww){ sv += s_u[tid * 16 + ww * 2]; qv += s_u[tid * 16 + ww * 2 + 1]; }
      const float mu = sv * (1.f / 512.f);
      s_mu[tid] = mu;
      s_rs[tid] = rsqrtf(qv * (1.f / 512.f) - mu * mu + EPSF);
    }
    __syncthreads();
    #pragma unroll
    for (int rt = 0; rt < 4; ++rt){
      #pragma unroll
      for (int r = 0; r < 4; ++r){
        const int zl = rt * 16 + 4 * g + r;
        const float mu = s_mu[zl], rs = s_rs[zl];
        #pragma unroll
        for (int ct = 0; ct < 4; ++ct){
          const int n = w * 64 + ct * 16 + al;
          const float val = (acc[rt][ct][r] - mu) * rs * mgr[ct] + mbnr[ct];
          s_A[((n >> 5) * 4 + rt) * 512 + ((4 * g + r) + 16 * ((n >> 3) & 3)) * 8 + (n & 7)] = f2bf(val);
        }
      }
    }
    __syncthreads();

    // ---------- GEMM2: vfin = h2n @ mW2; y += att * vfin ----------
    #pragma unroll
    for (int rt = 0; rt < 4; ++rt)
      #pragma unroll
      for (int ct = 0; ct < 4; ++ct) acc[rt][ct] = (f32x4){0,0,0,0};
    for (int s = 0; s < 16; ++s){
      bf16x8 bw[4];
      #pragma unroll
      for (int ct = 0; ct < 4; ++ct)
        bw[ct] = *(const bf16x8*)(W2p + (size_t)((s * 32 + w * 4 + ct) * 64 + L) * 8);
      #pragma unroll
      for (int rt = 0; rt < 4; ++rt){
        const bf16x8 a = *(const bf16x8*)(s_A + ((s * 4 + rt) * 64 + L) * 8);
        #pragma unroll
        for (int ct = 0; ct < 4; ++ct)
          acc[rt][ct] = __builtin_amdgcn_mfma_f32_16x16x32_bf16(a, bw[ct], acc[rt][ct], 0, 0, 0);
      }
    }
    {
      const float attp = pass ? att1 : att0;
      #pragma unroll
      for (int rt = 0; rt < 4; ++rt){
        #pragma unroll
        for (int r = 0; r < 4; ++r){
          const int zl = rt * 16 + 4 * g + r;
          const float aw = __shfl(attp, zl);
          #pragma unroll
          for (int ct = 0; ct < 4; ++ct) yv[ct] += aw * acc[rt][ct][r];
        }
      }
    }
  }

  // ---------- y reduce + write (wave w owns head w's cols) ----------
  #pragma unroll
  for (int ct = 0; ct < 4; ++ct){
    yv[ct] += __shfl_xor(yv[ct], 16);
    yv[ct] += __shfl_xor(yv[ct], 32);
  }
  if (g == 0){
    #pragma unroll
    for (int ct = 0; ct < 4; ++ct){
      const int n = w * 64 + ct * 16 + al;
      yout[(size_t)bc * 512 + n] = yv[ct] + mb2[n];
    }
  }
}

// ---------------- K5: out = y @ Wo + bo (f32) ----------------
__global__ __launch_bounds__(256) void eca_out(
    const float* __restrict__ y, const float* __restrict__ Wo, const float* __restrict__ bo,
    float* __restrict__ out)
{
  const int rt = blockIdx.x >> 2, ct = blockIdx.x & 3;    // 32 row-tiles x 4 col-tiles
  const int tid = threadIdx.x;
  __shared__ float s_y[16][512];
  const float* yb = y + (size_t)rt * 16 * 512;
  for (int i = tid; i < 16 * 128; i += 256)
    ((float4*)&s_y[0][0])[i] = ((const float4*)yb)[i];
  __syncthreads();
  const int jc = ct * 128 + (tid & 31) * 4;
  const int r0 = (tid >> 5) * 2;
  float acc[2][4] = {};
  #pragma unroll 4
  for (int k = 0; k < 512; ++k){
    const float4 wv = *(const float4*)(Wo + (size_t)k * 512 + jc);
    #pragma unroll
    for (int r = 0; r < 2; ++r){
      const float yvv = s_y[r0 + r][k];
      acc[r][0] += yvv * wv.x; acc[r][1] += yvv * wv.y;
      acc[r][2] += yvv * wv.z; acc[r][3] += yvv * wv.w;
    }
  }
  const float4 bv4 = *(const float4*)(bo + jc);
  #pragma unroll
  for (int r = 0; r < 2; ++r){
    float4 o;
    o.x = acc[r][0] + bv4.x; o.y = acc[r][1] + bv4.y;
    o.z = acc[r][2] + bv4.z; o.w = acc[r][3] + bv4.w;
    *(float4*)(out + (size_t)(rt * 16 + r0 + r) * 512 + jc) = o;
  }
}

extern "C" void kernel_launch(void* const* d_in, const int* in_sizes, int n_in,
                              void* d_out, int out_size, void* d_ws, size_t ws_size,
                              hipStream_t stream)
{
  const float* inputs = (const float*)d_in[0];
  const float* p   = (const float*)d_in[1];
  const float* a   = (const float*)d_in[2];
  const float* Bq  = (const float*)d_in[3];
  const float* Wqe = (const float*)d_in[4];
  const float* bqe = (const float*)d_in[5];
  const float* Bv  = (const float*)d_in[6];
  const float* Wve = (const float*)d_in[7];
  const float* bve = (const float*)d_in[8];
  const float* Wq  = (const float*)d_in[9];
  const float* bq  = (const float*)d_in[10];
  const float* Wk  = (const float*)d_in[11];
  const float* bk  = (const float*)d_in[12];
  const float* Wv  = (const float*)d_in[13];
  const float* bv  = (const float*)d_in[14];
  const float* vW1 = (const float*)d_in[15];
  const float* vb1 = (const float*)d_in[16];
  const float* vg  = (const float*)d_in[17];
  const float* vbn = (const float*)d_in[18];
  const float* vW2 = (const float*)d_in[19];
  const float* vb2 = (const float*)d_in[20];
  const float* mW1 = (const float*)d_in[21];
  const float* mb1 = (const float*)d_in[22];
  const float* mg  = (const float*)d_in[23];
  const float* mbn = (const float*)d_in[24];
  const float* mW2 = (const float*)d_in[25];
  const float* mb2 = (const float*)d_in[26];
  const float* Wo  = (const float*)d_in[27];
  const float* bo  = (const float*)d_in[28];
  (void)in_sizes; (void)n_in; (void)out_size; (void)ws_size;

  float* v0g  = (float*)d_ws;                        // 131072 f32
  float* kqf  = v0g + 131072;                        // 131072 f32
  float* bqkg = kqf + 131072;                        // 2048 f32
  float* yws  = bqkg + 2048;                         // 262144 f32
  ushort_t* W1p   = (ushort_t*)(yws + 262144);       // 262144 bf16
  ushort_t* W2p   = W1p + 262144;                    // 262144 bf16
  ushort_t* vW2p  = W2p + 262144;                    // 65536 bf16
  ushort_t* WveFp = vW2p + 65536;                    // 4096 bf16
  float* bveF = (float*)(WveFp + 4096);              // 64 f32
  float* out = (float*)d_out;

  eca_pack<<<dim3(1025), dim3(256), 0, stream>>>(mW1, mW2, vW2, Wve, vW1, bve, vb1,
                                                 W1p, W2p, vW2p, WveFp, bveF);
  eca_prep<<<dim3(NB * NZ), dim3(256), 0, stream>>>(a, Wk, bk, Wv, bv, Wq, bq, Wqe, bqe,
                                                    v0g, kqf, bqkg);
  eca_main<<<dim3(NB * NC), dim3(512), 0, stream>>>(
      inputs, p, Bq, Bv, vg, vbn, vb2, mb1, mg, mbn, mb2,
      v0g, kqf, bqkg, W1p, W2p, vW2p, WveFp, bveF, yws);
  eca_out<<<dim3(128), dim3(256), 0, stream>>>(yws, Wo, bo, out);
}

// Round 5
// 659.565 us; speedup vs baseline: 1.1490x; 1.1490x over previous
//
#include <hip/hip_runtime.h>
#include <hip/hip_bf16.h>
#include <math.h>

#define NB 2
#define NC 256
#define NZ 128
#define NHEADS 8
#define HDIM 64
#define HHID 512
#define EPSF 1e-5f
#define TWO_PI_F 6.283185307179586f

typedef __attribute__((ext_vector_type(8))) short bf16x8;
typedef __attribute__((ext_vector_type(4))) float f32x4;
typedef unsigned short ushort_t;

__device__ __forceinline__ float gelu_f(float x){
  const float u = 0.7978845608028654f * (x + 0.044715f * x * x * x);
  const float t = 1.0f - 2.0f / (__expf(2.0f * u) + 1.0f);  // tanh(u)
  return 0.5f * x * (1.0f + t);
}

__device__ __forceinline__ ushort_t f2bf(float x){
  unsigned int u = __float_as_uint(x);
  unsigned int r = ((u >> 16) & 1u) + 0x7fffu;   // round-to-nearest-even
  return (ushort_t)((u + r) >> 16);
}

// ---------------- K0: pack weights to bf16 MFMA-fragment order ----------------
// B-frag: idx=((s*T + t)*64 + L)*8 + j  <->  W[k=s*32+8*(L>>4)+j][n=16*t+(L&15)]
__global__ __launch_bounds__(256) void eca_pack(
    const float* __restrict__ mW1, const float* __restrict__ mW2, const float* __restrict__ vW2,
    const float* __restrict__ Wve, const float* __restrict__ vW1,
    const float* __restrict__ bve, const float* __restrict__ vb1,
    ushort_t* __restrict__ W1p, ushort_t* __restrict__ W2p, ushort_t* __restrict__ vW2p,
    ushort_t* __restrict__ WveFp, float* __restrict__ bveF)
{
  if (blockIdx.x == 1024){
    // fused front weight: WveF = Wve @ vW1 (64x64), bveF = bve@vW1 + vb1
    __shared__ float s_wf[64][64];
    const int tid = threadIdx.x;
    const int m = tid >> 2, iq = tid & 3;
    float accv[16];
    #pragma unroll
    for (int ii = 0; ii < 16; ++ii) accv[ii] = 0.f;
    for (int k = 0; k < 64; ++k){
      const float wv = Wve[m * 64 + k];
      const float4* vr = (const float4*)(vW1 + k * 64 + iq * 16);
      float t4[16];
      *(float4*)&t4[0] = vr[0]; *(float4*)&t4[4] = vr[1];
      *(float4*)&t4[8] = vr[2]; *(float4*)&t4[12] = vr[3];
      #pragma unroll
      for (int ii = 0; ii < 16; ++ii) accv[ii] += wv * t4[ii];
    }
    #pragma unroll
    for (int ii = 0; ii < 16; ++ii) s_wf[m][iq * 16 + ii] = accv[ii];
    if (tid < 64){
      float acc = vb1[tid];
      for (int k = 0; k < 64; ++k) acc += bve[k] * vW1[k * 64 + tid];
      bveF[tid] = acc;
    }
    __syncthreads();
    for (int e = tid; e < 4096; e += 256){
      const int j = e & 7, L = (e >> 3) & 63, t = (e >> 9) & 3, s = e >> 11;
      const int k = s * 32 + ((L >> 4) << 3) + j;
      const int n = (t << 4) + (L & 15);
      WveFp[e] = f2bf(s_wf[k][n]);
    }
    return;
  }
  const int i = blockIdx.x * 256 + threadIdx.x;
  {
    const int j = i & 7, L = (i >> 3) & 63, t = (i >> 9) & 31, s = i >> 14;
    const int k = s * 32 + ((L >> 4) << 3) + j;
    const int n = (t << 4) + (L & 15);
    W1p[i] = f2bf(mW1[k * 512 + n]);
    W2p[i] = f2bf(mW2[k * 512 + n]);
  }
  if (i < 65536){
    const int j = i & 7, L = (i >> 3) & 63, gb = (i >> 9) & 1, tp = (i >> 10) & 31, s = i >> 15;
    const int k = s * 32 + ((L >> 4) << 3) + j;
    const int n = (tp << 4) + (L & 15) + gb * 512;
    vW2p[i] = f2bf(vW2[k * 1024 + n]);
  }
}

// ---------------- K1: per-(b,z) latent precompute + KqF fold ----------------
__global__ __launch_bounds__(256) void eca_prep(
    const float* __restrict__ a, const float* __restrict__ Wk, const float* __restrict__ bk,
    const float* __restrict__ Wv, const float* __restrict__ bv,
    const float* __restrict__ Wq, const float* __restrict__ bq,
    const float* __restrict__ Wqe, const float* __restrict__ bqe,
    float* __restrict__ v0g, float* __restrict__ kqf, float* __restrict__ bqkg)
{
  const int bz = blockIdx.x;
  const int tid = threadIdx.x;
  __shared__ float s_a[64];
  __shared__ float s_k[512];
  __shared__ float s_kq[512];
  if (tid < 64) s_a[tid] = a[bz * 64 + tid];
  __syncthreads();
  #pragma unroll
  for (int jo = 0; jo < 2; ++jo){
    const int j = tid + jo * 256;
    float accK = bk[j], accV = bv[j];
    for (int i = 0; i < 64; ++i){
      const float av = s_a[i];
      accK += av * Wk[i * 512 + j];
      accV += av * Wv[i * 512 + j];
    }
    s_k[j] = accK;
    v0g[(size_t)bz * 512 + j] = accV;
  }
  __syncthreads();
  // Kq[h,i] = sum_j Wq[i, h*64+j] * k[h*64+j]
  #pragma unroll
  for (int io = 0; io < 2; ++io){
    const int idx = tid + io * 256;
    const int h = idx >> 6, i = idx & 63;
    float acc = 0.f;
    for (int j = 0; j < 64; ++j)
      acc += Wq[i * 512 + h * 64 + j] * s_k[h * 64 + j];
    s_kq[idx] = acc;
  }
  __syncthreads();
  // KqF[m,h] = sum_i Wqe[m,i] * Kq[h,i]; layout kqf[bz*512 + (m>>4)*128 + h*16 + (m&15)]
  #pragma unroll
  for (int io = 0; io < 2; ++io){
    const int idx = tid + io * 256;
    const int m = idx >> 3, h = idx & 7;
    float acc = 0.f;
    for (int i = 0; i < 64; ++i) acc += Wqe[m * 64 + i] * s_kq[h * 64 + i];
    kqf[(size_t)bz * 512 + (m >> 4) * 128 + h * 16 + (m & 15)] = acc;
  }
  if (tid < 8){
    float acc = 0.f;
    for (int j = 0; j < 64; ++j) acc += bq[tid * 64 + j] * s_k[tid * 64 + j];
    for (int i = 0; i < 64; ++i) acc += bqe[i] * s_kq[tid * 64 + i];
    bqkg[bz * 8 + tid] = acc;
  }
}

// ---------------- K3: fused per-(b,c), two 64-z passes, 78KB LDS, 2 blocks/CU ----------------
__global__ __launch_bounds__(512, 2) void eca_main(
    const float* __restrict__ inputs, const float* __restrict__ p,
    const float* __restrict__ Bq, const float* __restrict__ Bv,
    const float* __restrict__ vg, const float* __restrict__ vbn,
    const float* __restrict__ vb2,
    const float* __restrict__ mb1, const float* __restrict__ mg, const float* __restrict__ mbn,
    const float* __restrict__ mb2,
    const float* __restrict__ v0g, const float* __restrict__ kqf, const float* __restrict__ bqkg,
    const ushort_t* __restrict__ W1p, const ushort_t* __restrict__ W2p, const ushort_t* __restrict__ vW2p,
    const ushort_t* __restrict__ WveFp, const float* __restrict__ bveF,
    float* __restrict__ yout)
{
  const int bc = blockIdx.x;
  const int b = bc >> 8;
  const int tid = threadIdx.x;
  const int w = tid >> 6, L = tid & 63;
  const int al = L & 15, g = L >> 4;
  const int bz0 = b * NZ;

  __shared__ __align__(16) ushort_t s_A[16 * 4 * 64 * 8];   // 64KB A-frags (64 z x 512)
  __shared__ __align__(16) ushort_t s_HN[2 * 4 * 64 * 8];   // 8KB hn frags (64 z x 64)
  __shared__ float s_u[1024];                                // union: logits[8][128] / ln64 / ln512
  __shared__ float s_mu[64], s_rs[64];
  __shared__ float s_qpt[3];

  if (tid < 3) s_qpt[tid] = inputs[bc * 3 + tid];
  __syncthreads();

  // ---------- logits: thread (z = tid>>2, q = tid&3); lg[h] = sum_m f_q[m]*KqF[z,h,m] ----------
  {
    const int z = tid >> 2, q = tid & 3;
    const float iv0 = s_qpt[0] - p[(bz0 + z) * 3 + 0];
    const float iv1 = s_qpt[1] - p[(bz0 + z) * 3 + 1];
    const float iv2 = s_qpt[2] - p[(bz0 + z) * 3 + 2];
    float tr[16];
    #pragma unroll
    for (int mi = 0; mi < 16; ++mi){
      const int mb = (q & 1) * 16 + mi;
      const float pr = TWO_PI_F * (iv0 * Bq[mb] + iv1 * Bq[32 + mb] + iv2 * Bq[64 + mb]);
      float sn, cn; sincosf(pr, &sn, &cn);
      tr[mi] = (q < 2) ? sn : cn;
    }
    const float* kfb = kqf + (size_t)(bz0 + z) * 512 + q * 128;
    float lg[8];
    #pragma unroll
    for (int h = 0; h < 8; ++h){
      const float4 k0 = *(const float4*)(kfb + h * 16);
      const float4 k1 = *(const float4*)(kfb + h * 16 + 4);
      const float4 k2 = *(const float4*)(kfb + h * 16 + 8);
      const float4 k3 = *(const float4*)(kfb + h * 16 + 12);
      lg[h] = tr[0]*k0.x + tr[1]*k0.y + tr[2]*k0.z + tr[3]*k0.w
            + tr[4]*k1.x + tr[5]*k1.y + tr[6]*k1.z + tr[7]*k1.w
            + tr[8]*k2.x + tr[9]*k2.y + tr[10]*k2.z + tr[11]*k2.w
            + tr[12]*k3.x + tr[13]*k3.y + tr[14]*k3.z + tr[15]*k3.w;
    }
    #pragma unroll
    for (int h = 0; h < 8; ++h){
      lg[h] += __shfl_xor(lg[h], 1);
      lg[h] += __shfl_xor(lg[h], 2);
    }
    const int h0 = q * 2;
    s_u[h0 * 128 + z]       = (lg[h0]     + bqkg[(bz0 + z) * 8 + h0])     * 0.125f;
    s_u[(h0 + 1) * 128 + z] = (lg[h0 + 1] + bqkg[(bz0 + z) * 8 + h0 + 1]) * 0.125f;
  }
  __syncthreads();

  // ---------- softmax (head w per wave) -> att in registers ----------
  float att0, att1;
  {
    const float x0 = s_u[w * 128 + L], x1 = s_u[w * 128 + L + 64];
    float mx = fmaxf(x0, x1);
    #pragma unroll
    for (int off = 32; off; off >>= 1) mx = fmaxf(mx, __shfl_xor(mx, off));
    const float e0 = __expf(x0 - mx), e1 = __expf(x1 - mx);
    float sm = e0 + e1;
    #pragma unroll
    for (int off = 32; off; off >>= 1) sm += __shfl_xor(sm, off);
    const float inv = 1.f / sm;
    att0 = e0 * inv; att1 = e1 * inv;
  }

  // per-thread constants
  const int rtf = w & 3, ch2 = w >> 2;          // front roles
  float vgr[2], vbnr[2], bver[2];
  #pragma unroll
  for (int ct = 0; ct < 2; ++ct){
    const int n = ch2 * 32 + ct * 16 + al;
    vgr[ct] = vg[n]; vbnr[ct] = vbn[n]; bver[ct] = bveF[n];
  }
  float mb1r[4], mgr[4], mbnr[4];
  #pragma unroll
  for (int ct = 0; ct < 4; ++ct){
    const int n = w * 64 + ct * 16 + al;
    mb1r[ct] = mb1[n]; mgr[ct] = mg[n]; mbnr[ct] = mbn[n];
  }
  float yv[4] = {0.f, 0.f, 0.f, 0.f};

  for (int pass = 0; pass < 2; ++pass){
    const int zp = pass * 64;
    __syncthreads();                                   // protect s_u / s_A reuse

    // ---------- front: hn = LN64(gelu(f @ WveF + bveF)); A-frags in registers ----------
    {
      const int zz = bz0 + zp + rtf * 16 + al;
      const float iv0 = s_qpt[0] - p[zz * 3 + 0];
      const float iv1 = s_qpt[1] - p[zz * 3 + 1];
      const float iv2 = s_qpt[2] - p[zz * 3 + 2];
      bf16x8 fa0, fa1;
      #pragma unroll
      for (int j = 0; j < 8; ++j){
        const int m = g * 8 + j;
        const float pr = TWO_PI_F * (iv0 * Bv[m] + iv1 * Bv[32 + m] + iv2 * Bv[64 + m]);
        float sn, cn; sincosf(pr, &sn, &cn);
        fa0[j] = (short)f2bf(sn);
        fa1[j] = (short)f2bf(cn);
      }
      f32x4 accf[2] = {{0,0,0,0},{0,0,0,0}};
      #pragma unroll
      for (int ct = 0; ct < 2; ++ct){
        const int t = ch2 * 2 + ct;
        const bf16x8 b0 = *(const bf16x8*)(WveFp + ((0 * 4 + t) * 64 + L) * 8);
        const bf16x8 b1 = *(const bf16x8*)(WveFp + ((1 * 4 + t) * 64 + L) * 8);
        accf[ct] = __builtin_amdgcn_mfma_f32_16x16x32_bf16(fa0, b0, accf[ct], 0, 0, 0);
        accf[ct] = __builtin_amdgcn_mfma_f32_16x16x32_bf16(fa1, b1, accf[ct], 0, 0, 0);
      }
      float h1v[2][4];
      #pragma unroll
      for (int r = 0; r < 4; ++r){
        float sv = 0.f, qv = 0.f;
        #pragma unroll
        for (int ct = 0; ct < 2; ++ct){
          const float v = gelu_f(accf[ct][r] + bver[ct]);
          h1v[ct][r] = v; sv += v; qv += v * v;
        }
        sv += __shfl_xor(sv, 1); sv += __shfl_xor(sv, 2);
        sv += __shfl_xor(sv, 4); sv += __shfl_xor(sv, 8);
        qv += __shfl_xor(qv, 1); qv += __shfl_xor(qv, 2);
        qv += __shfl_xor(qv, 4); qv += __shfl_xor(qv, 8);
        if (al == 0){
          const int row = rtf * 16 + 4 * g + r;
          s_u[row * 4 + ch2 * 2 + 0] = sv;
          s_u[row * 4 + ch2 * 2 + 1] = qv;
        }
      }
      __syncthreads();
      #pragma unroll
      for (int r = 0; r < 4; ++r){
        const int row = rtf * 16 + 4 * g + r;
        const float sv = s_u[row * 4 + 0] + s_u[row * 4 + 2];
        const float qv = s_u[row * 4 + 1] + s_u[row * 4 + 3];
        const float mu = sv * (1.f / 64.f);
        const float rs = rsqrtf(qv * (1.f / 64.f) - mu * mu + EPSF);
        #pragma unroll
        for (int ct = 0; ct < 2; ++ct){
          const int n = ch2 * 32 + ct * 16 + al;
          const float val = (h1v[ct][r] - mu) * rs * vgr[ct] + vbnr[ct];
          s_HN[((n >> 5) * 4 + rtf) * 512 + ((4 * g + r) + 16 * ((n >> 3) & 3)) * 8 + (n & 7)] = f2bf(val);
        }
      }
    }
    __syncthreads();

    // ---------- gb MFMA: hn[64x64] @ vW2[64x1024] -> FiLM -> vfilm frags in s_A ----------
    #pragma unroll
    for (int ch = 0; ch < 2; ++ch){
      f32x4 accg[2][4], accb[2][4];
      #pragma unroll
      for (int ti = 0; ti < 2; ++ti)
        #pragma unroll
        for (int rt = 0; rt < 4; ++rt){ accg[ti][rt] = (f32x4){0,0,0,0}; accb[ti][rt] = (f32x4){0,0,0,0}; }
      #pragma unroll
      for (int s = 0; s < 2; ++s){
        bf16x8 afr[4];
        #pragma unroll
        for (int rt = 0; rt < 4; ++rt)
          afr[rt] = *(const bf16x8*)(s_HN + ((s * 4 + rt) * 64 + L) * 8);
        #pragma unroll
        for (int ti = 0; ti < 2; ++ti){
          const int tp = w * 4 + ch * 2 + ti;
          const bf16x8 bg = *(const bf16x8*)(vW2p + (size_t)(((s * 32 + tp) * 2 + 0) * 64 + L) * 8);
          const bf16x8 bb = *(const bf16x8*)(vW2p + (size_t)(((s * 32 + tp) * 2 + 1) * 64 + L) * 8);
          #pragma unroll
          for (int rt = 0; rt < 4; ++rt){
            accg[ti][rt] = __builtin_amdgcn_mfma_f32_16x16x32_bf16(afr[rt], bg, accg[ti][rt], 0, 0, 0);
            accb[ti][rt] = __builtin_amdgcn_mfma_f32_16x16x32_bf16(afr[rt], bb, accb[ti][rt], 0, 0, 0);
          }
        }
      }
      #pragma unroll
      for (int ti = 0; ti < 2; ++ti){
        const int n = (w * 4 + ch * 2 + ti) * 16 + al;
        const float gbias = vb2[n], bbias = vb2[512 + n];
        #pragma unroll
        for (int rt = 0; rt < 4; ++rt){
          #pragma unroll
          for (int r = 0; r < 4; ++r){
            const int zl = rt * 16 + 4 * g + r;
            const float v0v = v0g[(size_t)(bz0 + zp + zl) * 512 + n];
            const float vf = v0v * (1.f + accg[ti][rt][r] + gbias) + (accb[ti][rt][r] + bbias);
            s_A[((n >> 5) * 4 + rt) * 512 + ((4 * g + r) + 16 * ((n >> 3) & 3)) * 8 + (n & 7)] = f2bf(vf);
          }
        }
      }
    }
    __syncthreads();

    // ---------- GEMM1: h2 = vfilm @ mW1; gelu + LN512 -> h2n back to s_A ----------
    f32x4 acc[4][4];
    #pragma unroll
    for (int rt = 0; rt < 4; ++rt)
      #pragma unroll
      for (int ct = 0; ct < 4; ++ct) acc[rt][ct] = (f32x4){0,0,0,0};
    for (int s = 0; s < 16; ++s){
      bf16x8 bw[4];
      #pragma unroll
      for (int ct = 0; ct < 4; ++ct)
        bw[ct] = *(const bf16x8*)(W1p + (size_t)((s * 32 + w * 4 + ct) * 64 + L) * 8);
      #pragma unroll
      for (int rt = 0; rt < 4; ++rt){
        const bf16x8 a = *(const bf16x8*)(s_A + ((s * 4 + rt) * 64 + L) * 8);
        #pragma unroll
        for (int ct = 0; ct < 4; ++ct)
          acc[rt][ct] = __builtin_amdgcn_mfma_f32_16x16x32_bf16(a, bw[ct], acc[rt][ct], 0, 0, 0);
      }
    }
    #pragma unroll
    for (int rt = 0; rt < 4; ++rt){
      #pragma unroll
      for (int r = 0; r < 4; ++r){
        float sv = 0.f, qv = 0.f;
        #pragma unroll
        for (int ct = 0; ct < 4; ++ct){
          const float v = gelu_f(acc[rt][ct][r] + mb1r[ct]);
          acc[rt][ct][r] = v; sv += v; qv += v * v;
        }
        sv += __shfl_xor(sv, 1); sv += __shfl_xor(sv, 2);
        sv += __shfl_xor(sv, 4); sv += __shfl_xor(sv, 8);
        qv += __shfl_xor(qv, 1); qv += __shfl_xor(qv, 2);
        qv += __shfl_xor(qv, 4); qv += __shfl_xor(qv, 8);
        if (al == 0){
          const int zl = rt * 16 + 4 * g + r;
          s_u[zl * 16 + w * 2 + 0] = sv;
          s_u[zl * 16 + w * 2 + 1] = qv;
        }
      }
    }
    __syncthreads();                    // also: all GEMM1 reads of s_A done
    if (tid < 64){
      float sv = 0.f, qv = 0.f;
      #pragma unroll
      for (int ww = 0; ww < 8; ++ww){ sv += s_u[tid * 16 + ww * 2]; qv += s_u[tid * 16 + ww * 2 + 1]; }
      const float mu = sv * (1.f / 512.f);
      s_mu[tid] = mu;
      s_rs[tid] = rsqrtf(qv * (1.f / 512.f) - mu * mu + EPSF);
    }
    __syncthreads();
    #pragma unroll
    for (int rt = 0; rt < 4; ++rt){
      #pragma unroll
      for (int r = 0; r < 4; ++r){
        const int zl = rt * 16 + 4 * g + r;
        const float mu = s_mu[zl], rs = s_rs[zl];
        #pragma unroll
        for (int ct = 0; ct < 4; ++ct){
          const int n = w * 64 + ct * 16 + al;
          const float val = (acc[rt][ct][r] - mu) * rs * mgr[ct] + mbnr[ct];
          s_A[((n >> 5) * 4 + rt) * 512 + ((4 * g + r) + 16 * ((n >> 3) & 3)) * 8 + (n & 7)] = f2bf(val);
        }
      }
    }
    __syncthreads();

    // ---------- GEMM2: vfin = h2n @ mW2; y += att * vfin ----------
    #pragma unroll
    for (int rt = 0; rt < 4; ++rt)
      #pragma unroll
      for (int ct = 0; ct < 4; ++ct) acc[rt][ct] = (f32x4){0,0,0,0};
    for (int s = 0; s < 16; ++s){
      bf16x8 bw[4];
      #pragma unroll
      for (int ct = 0; ct < 4; ++ct)
        bw[ct] = *(const bf16x8*)(W2p + (size_t)((s * 32 + w * 4 + ct) * 64 + L) * 8);
      #pragma unroll
      for (int rt = 0; rt < 4; ++rt){
        const bf16x8 a = *(const bf16x8*)(s_A + ((s * 4 + rt) * 64 + L) * 8);
        #pragma unroll
        for (int ct = 0; ct < 4; ++ct)
          acc[rt][ct] = __builtin_amdgcn_mfma_f32_16x16x32_bf16(a, bw[ct], acc[rt][ct], 0, 0, 0);
      }
    }
    {
      const float attp = pass ? att1 : att0;
      #pragma unroll
      for (int rt = 0; rt < 4; ++rt){
        #pragma unroll
        for (int r = 0; r < 4; ++r){
          const int zl = rt * 16 + 4 * g + r;
          const float aw = __shfl(attp, zl);
          #pragma unroll
          for (int ct = 0; ct < 4; ++ct) yv[ct] += aw * acc[rt][ct][r];
        }
      }
    }
  }

  // ---------- y reduce + write (wave w owns head w's cols) ----------
  #pragma unroll
  for (int ct = 0; ct < 4; ++ct){
    yv[ct] += __shfl_xor(yv[ct], 16);
    yv[ct] += __shfl_xor(yv[ct], 32);
  }
  if (g == 0){
    #pragma unroll
    for (int ct = 0; ct < 4; ++ct){
      const int n = w * 64 + ct * 16 + al;
      yout[(size_t)bc * 512 + n] = yv[ct] + mb2[n];
    }
  }
}

// ---------------- K5: out = y @ Wo + bo (f32) ----------------
__global__ __launch_bounds__(256) void eca_out(
    const float* __restrict__ y, const float* __restrict__ Wo, const float* __restrict__ bo,
    float* __restrict__ out)
{
  const int rt = blockIdx.x >> 2, ct = blockIdx.x & 3;    // 32 row-tiles x 4 col-tiles
  const int tid = threadIdx.x;
  __shared__ float s_y[16][512];
  const float* yb = y + (size_t)rt * 16 * 512;
  for (int i = tid; i < 16 * 128; i += 256)
    ((float4*)&s_y[0][0])[i] = ((const float4*)yb)[i];
  __syncthreads();
  const int jc = ct * 128 + (tid & 31) * 4;
  const int r0 = (tid >> 5) * 2;
  float acc[2][4] = {};
  #pragma unroll 4
  for (int k = 0; k < 512; ++k){
    const float4 wv = *(const float4*)(Wo + (size_t)k * 512 + jc);
    #pragma unroll
    for (int r = 0; r < 2; ++r){
      const float yvv = s_y[r0 + r][k];
      acc[r][0] += yvv * wv.x; acc[r][1] += yvv * wv.y;
      acc[r][2] += yvv * wv.z; acc[r][3] += yvv * wv.w;
    }
  }
  const float4 bv4 = *(const float4*)(bo + jc);
  #pragma unroll
  for (int r = 0; r < 2; ++r){
    float4 o;
    o.x = acc[r][0] + bv4.x; o.y = acc[r][1] + bv4.y;
    o.z = acc[r][2] + bv4.z; o.w = acc[r][3] + bv4.w;
    *(float4*)(out + (size_t)(rt * 16 + r0 + r) * 512 + jc) = o;
  }
}

extern "C" void kernel_launch(void* const* d_in, const int* in_sizes, int n_in,
                              void* d_out, int out_size, void* d_ws, size_t ws_size,
                              hipStream_t stream)
{
  const float* inputs = (const float*)d_in[0];
  const float* p   = (const float*)d_in[1];
  const float* a   = (const float*)d_in[2];
  const float* Bq  = (const float*)d_in[3];
  const float* Wqe = (const float*)d_in[4];
  const float* bqe = (const float*)d_in[5];
  const float* Bv  = (const float*)d_in[6];
  const float* Wve = (const float*)d_in[7];
  const float* bve = (const float*)d_in[8];
  const float* Wq  = (const float*)d_in[9];
  const float* bq  = (const float*)d_in[10];
  const float* Wk  = (const float*)d_in[11];
  const float* bk  = (const float*)d_in[12];
  const float* Wv  = (const float*)d_in[13];
  const float* bv  = (const float*)d_in[14];
  const float* vW1 = (const float*)d_in[15];
  const float* vb1 = (const float*)d_in[16];
  const float* vg  = (const float*)d_in[17];
  const float* vbn = (const float*)d_in[18];
  const float* vW2 = (const float*)d_in[19];
  const float* vb2 = (const float*)d_in[20];
  const float* mW1 = (const float*)d_in[21];
  const float* mb1 = (const float*)d_in[22];
  const float* mg  = (const float*)d_in[23];
  const float* mbn = (const float*)d_in[24];
  const float* mW2 = (const float*)d_in[25];
  const float* mb2 = (const float*)d_in[26];
  const float* Wo  = (const float*)d_in[27];
  const float* bo  = (const float*)d_in[28];
  (void)in_sizes; (void)n_in; (void)out_size; (void)ws_size;

  float* v0g  = (float*)d_ws;                        // 131072 f32
  float* kqf  = v0g + 131072;                        // 131072 f32
  float* bqkg = kqf + 131072;                        // 2048 f32
  float* yws  = bqkg + 2048;                         // 262144 f32
  ushort_t* W1p   = (ushort_t*)(yws + 262144);       // 262144 bf16
  ushort_t* W2p   = W1p + 262144;                    // 262144 bf16
  ushort_t* vW2p  = W2p + 262144;                    // 65536 bf16
  ushort_t* WveFp = vW2p + 65536;                    // 4096 bf16
  float* bveF = (float*)(WveFp + 4096);              // 64 f32
  float* out = (float*)d_out;

  eca_pack<<<dim3(1025), dim3(256), 0, stream>>>(mW1, mW2, vW2, Wve, vW1, bve, vb1,
                                                 W1p, W2p, vW2p, WveFp, bveF);
  eca_prep<<<dim3(NB * NZ), dim3(256), 0, stream>>>(a, Wk, bk, Wv, bv, Wq, bq, Wqe, bqe,
                                                    v0g, kqf, bqkg);
  eca_main<<<dim3(NB * NC), dim3(512), 0, stream>>>(
      inputs, p, Bq, Bv, vg, vbn, vb2, mb1, mg, mbn, mb2,
      v0g, kqf, bqkg, W1p, W2p, vW2p, WveFp, bveF, yws);
  eca_out<<<dim3(128), dim3(256), 0, stream>>>(yws, Wo, bo, out);
}

// Round 6
// 362.657 us; speedup vs baseline: 2.0896x; 1.8187x over previous
//
#include <hip/hip_runtime.h>
#include <hip/hip_bf16.h>
#include <math.h>

#define NB 2
#define NC 256
#define NZ 128
#define NHEADS 8
#define HDIM 64
#define HHID 512
#define EPSF 1e-5f
#define TWO_PI_F 6.283185307179586f

typedef __attribute__((ext_vector_type(8))) short bf16x8;
typedef __attribute__((ext_vector_type(4))) float f32x4;
typedef unsigned short ushort_t;

__device__ __forceinline__ float gelu_f(float x){
  const float u = 0.7978845608028654f * (x + 0.044715f * x * x * x);
  const float t = 1.0f - 2.0f / (__expf(2.0f * u) + 1.0f);  // tanh(u)
  return 0.5f * x * (1.0f + t);
}

__device__ __forceinline__ ushort_t f2bf(float x){
  unsigned int u = __float_as_uint(x);
  unsigned int r = ((u >> 16) & 1u) + 0x7fffu;   // round-to-nearest-even
  return (ushort_t)((u + r) >> 16);
}

// ---------------- K0: pack weights to bf16 MFMA-fragment order ----------------
// B-frag: idx=((s*T + t)*64 + L)*8 + j  <->  W[k=s*32+8*(L>>4)+j][n=16*t+(L&15)]
__global__ __launch_bounds__(256) void eca_pack(
    const float* __restrict__ mW1, const float* __restrict__ mW2, const float* __restrict__ vW2,
    const float* __restrict__ Wve, const float* __restrict__ vW1,
    const float* __restrict__ bve, const float* __restrict__ vb1,
    ushort_t* __restrict__ W1p, ushort_t* __restrict__ W2p, ushort_t* __restrict__ vW2p,
    ushort_t* __restrict__ WveFp, float* __restrict__ bveF)
{
  if (blockIdx.x == 1024){
    // fused front weight: WveF = Wve @ vW1 (64x64), bveF = bve@vW1 + vb1
    __shared__ float s_wf[64][64];
    const int tid = threadIdx.x;
    const int m = tid >> 2, iq = tid & 3;
    float accv[16];
    #pragma unroll
    for (int ii = 0; ii < 16; ++ii) accv[ii] = 0.f;
    for (int k = 0; k < 64; ++k){
      const float wv = Wve[m * 64 + k];
      const float4* vr = (const float4*)(vW1 + k * 64 + iq * 16);
      float t4[16];
      *(float4*)&t4[0] = vr[0]; *(float4*)&t4[4] = vr[1];
      *(float4*)&t4[8] = vr[2]; *(float4*)&t4[12] = vr[3];
      #pragma unroll
      for (int ii = 0; ii < 16; ++ii) accv[ii] += wv * t4[ii];
    }
    #pragma unroll
    for (int ii = 0; ii < 16; ++ii) s_wf[m][iq * 16 + ii] = accv[ii];
    if (tid < 64){
      float acc = vb1[tid];
      for (int k = 0; k < 64; ++k) acc += bve[k] * vW1[k * 64 + tid];
      bveF[tid] = acc;
    }
    __syncthreads();
    for (int e = tid; e < 4096; e += 256){
      const int j = e & 7, L = (e >> 3) & 63, t = (e >> 9) & 3, s = e >> 11;
      const int k = s * 32 + ((L >> 4) << 3) + j;
      const int n = (t << 4) + (L & 15);
      WveFp[e] = f2bf(s_wf[k][n]);
    }
    return;
  }
  const int i = blockIdx.x * 256 + threadIdx.x;
  {
    const int j = i & 7, L = (i >> 3) & 63, t = (i >> 9) & 31, s = i >> 14;
    const int k = s * 32 + ((L >> 4) << 3) + j;
    const int n = (t << 4) + (L & 15);
    W1p[i] = f2bf(mW1[k * 512 + n]);
    W2p[i] = f2bf(mW2[k * 512 + n]);
  }
  if (i < 65536){
    const int j = i & 7, L = (i >> 3) & 63, gb = (i >> 9) & 1, tp = (i >> 10) & 31, s = i >> 15;
    const int k = s * 32 + ((L >> 4) << 3) + j;
    const int n = (tp << 4) + (L & 15) + gb * 512;
    vW2p[i] = f2bf(vW2[k * 1024 + n]);
  }
}

// ---------------- K1: per-(b,z) latent precompute + KqF fold ----------------
__global__ __launch_bounds__(256) void eca_prep(
    const float* __restrict__ a, const float* __restrict__ Wk, const float* __restrict__ bk,
    const float* __restrict__ Wv, const float* __restrict__ bv,
    const float* __restrict__ Wq, const float* __restrict__ bq,
    const float* __restrict__ Wqe, const float* __restrict__ bqe,
    float* __restrict__ v0g, float* __restrict__ kqf, float* __restrict__ bqkg)
{
  const int bz = blockIdx.x;
  const int tid = threadIdx.x;
  __shared__ float s_a[64];
  __shared__ float s_k[512];
  __shared__ float s_kq[512];
  if (tid < 64) s_a[tid] = a[bz * 64 + tid];
  __syncthreads();
  #pragma unroll
  for (int jo = 0; jo < 2; ++jo){
    const int j = tid + jo * 256;
    float accK = bk[j], accV = bv[j];
    for (int i = 0; i < 64; ++i){
      const float av = s_a[i];
      accK += av * Wk[i * 512 + j];
      accV += av * Wv[i * 512 + j];
    }
    s_k[j] = accK;
    v0g[(size_t)bz * 512 + j] = accV;
  }
  __syncthreads();
  // Kq[h,i] = sum_j Wq[i, h*64+j] * k[h*64+j]
  #pragma unroll
  for (int io = 0; io < 2; ++io){
    const int idx = tid + io * 256;
    const int h = idx >> 6, i = idx & 63;
    float acc = 0.f;
    for (int j = 0; j < 64; ++j)
      acc += Wq[i * 512 + h * 64 + j] * s_k[h * 64 + j];
    s_kq[idx] = acc;
  }
  __syncthreads();
  // KqF[m,h] = sum_i Wqe[m,i] * Kq[h,i]; layout kqf[bz*512 + (m>>4)*128 + h*16 + (m&15)]
  #pragma unroll
  for (int io = 0; io < 2; ++io){
    const int idx = tid + io * 256;
    const int m = idx >> 3, h = idx & 7;
    float acc = 0.f;
    for (int i = 0; i < 64; ++i) acc += Wqe[m * 64 + i] * s_kq[h * 64 + i];
    kqf[(size_t)bz * 512 + (m >> 4) * 128 + h * 16 + (m & 15)] = acc;
  }
  if (tid < 8){
    float acc = 0.f;
    for (int j = 0; j < 64; ++j) acc += bq[tid * 64 + j] * s_k[tid * 64 + j];
    for (int i = 0; i < 64; ++i) acc += bqe[i] * s_kq[tid * 64 + i];
    bqkg[bz * 8 + tid] = acc;
  }
}

// 64-z-pass 512x512 GEMM step: wave owns all 64 rows x its 64 cols.
// Ping-pong B prefetch (named arrays, no runtime indexing); #pragma unroll 1
// keeps the K-loop rolled so the compiler cannot hoist all 64 B-loads (spill fix).
__device__ __forceinline__ void gemm_pass(f32x4 (&acc)[4][4], const ushort_t* __restrict__ Wp,
                                          const ushort_t* sA, const int w, const int L)
{
  bf16x8 b0[4], b1[4];
  #pragma unroll
  for (int ct = 0; ct < 4; ++ct)
    b0[ct] = *(const bf16x8*)(Wp + (size_t)((w * 4 + ct) * 64 + L) * 8);
  #pragma unroll 1
  for (int s2 = 0; s2 < 8; ++s2){
    const int s = 2 * s2;
    #pragma unroll
    for (int ct = 0; ct < 4; ++ct)
      b1[ct] = *(const bf16x8*)(Wp + (size_t)(((s + 1) * 32 + w * 4 + ct) * 64 + L) * 8);
    #pragma unroll
    for (int rt = 0; rt < 4; ++rt){
      const bf16x8 a = *(const bf16x8*)(sA + ((s * 4 + rt) * 64 + L) * 8);
      #pragma unroll
      for (int ct = 0; ct < 4; ++ct)
        acc[rt][ct] = __builtin_amdgcn_mfma_f32_16x16x32_bf16(a, b0[ct], acc[rt][ct], 0, 0, 0);
    }
    const int sn = (s2 < 7) ? (s + 2) : 0;
    #pragma unroll
    for (int ct = 0; ct < 4; ++ct)
      b0[ct] = *(const bf16x8*)(Wp + (size_t)((sn * 32 + w * 4 + ct) * 64 + L) * 8);
    #pragma unroll
    for (int rt = 0; rt < 4; ++rt){
      const bf16x8 a = *(const bf16x8*)(sA + (((s + 1) * 4 + rt) * 64 + L) * 8);
      #pragma unroll
      for (int ct = 0; ct < 4; ++ct)
        acc[rt][ct] = __builtin_amdgcn_mfma_f32_16x16x32_bf16(a, b1[ct], acc[rt][ct], 0, 0, 0);
    }
  }
}

// ---------------- K3: fused per-(b,c), two 64-z passes, 78KB LDS ----------------
__global__ __launch_bounds__(512, 2) void eca_main(
    const float* __restrict__ inputs, const float* __restrict__ p,
    const float* __restrict__ Bq, const float* __restrict__ Bv,
    const float* __restrict__ vg, const float* __restrict__ vbn,
    const float* __restrict__ vb2,
    const float* __restrict__ mb1, const float* __restrict__ mg, const float* __restrict__ mbn,
    const float* __restrict__ mb2,
    const float* __restrict__ v0g, const float* __restrict__ kqf, const float* __restrict__ bqkg,
    const ushort_t* __restrict__ W1p, const ushort_t* __restrict__ W2p, const ushort_t* __restrict__ vW2p,
    const ushort_t* __restrict__ WveFp, const float* __restrict__ bveF,
    float* __restrict__ yout)
{
  const int bc = blockIdx.x;
  const int b = bc >> 8;
  const int tid = threadIdx.x;
  const int w = tid >> 6, L = tid & 63;
  const int al = L & 15, g = L >> 4;
  const int bz0 = b * NZ;

  __shared__ __align__(16) ushort_t s_A[16 * 4 * 64 * 8];   // 64KB A-frags (64 z x 512)
  __shared__ __align__(16) ushort_t s_HN[2 * 4 * 64 * 8];   // 8KB hn frags (64 z x 64)
  __shared__ float s_u[1024];                                // union: logits[8][128] / ln64 / ln512
  __shared__ float s_mu[64], s_rs[64];
  __shared__ float s_qpt[3];

  if (tid < 3) s_qpt[tid] = inputs[bc * 3 + tid];
  __syncthreads();

  // ---------- logits: thread (z = tid>>2, q = tid&3); lg[h] = sum_m f_q[m]*KqF[z,h,m] ----------
  {
    const int z = tid >> 2, q = tid & 3;
    const float iv0 = s_qpt[0] - p[(bz0 + z) * 3 + 0];
    const float iv1 = s_qpt[1] - p[(bz0 + z) * 3 + 1];
    const float iv2 = s_qpt[2] - p[(bz0 + z) * 3 + 2];
    float tr[16];
    #pragma unroll
    for (int mi = 0; mi < 16; ++mi){
      const int mb = (q & 1) * 16 + mi;
      const float pr = TWO_PI_F * (iv0 * Bq[mb] + iv1 * Bq[32 + mb] + iv2 * Bq[64 + mb]);
      float sn, cn; sincosf(pr, &sn, &cn);
      tr[mi] = (q < 2) ? sn : cn;
    }
    const float* kfb = kqf + (size_t)(bz0 + z) * 512 + q * 128;
    float lg[8];
    #pragma unroll
    for (int h = 0; h < 8; ++h){
      const float4 k0 = *(const float4*)(kfb + h * 16);
      const float4 k1 = *(const float4*)(kfb + h * 16 + 4);
      const float4 k2 = *(const float4*)(kfb + h * 16 + 8);
      const float4 k3 = *(const float4*)(kfb + h * 16 + 12);
      lg[h] = tr[0]*k0.x + tr[1]*k0.y + tr[2]*k0.z + tr[3]*k0.w
            + tr[4]*k1.x + tr[5]*k1.y + tr[6]*k1.z + tr[7]*k1.w
            + tr[8]*k2.x + tr[9]*k2.y + tr[10]*k2.z + tr[11]*k2.w
            + tr[12]*k3.x + tr[13]*k3.y + tr[14]*k3.z + tr[15]*k3.w;
    }
    #pragma unroll
    for (int h = 0; h < 8; ++h){
      lg[h] += __shfl_xor(lg[h], 1);
      lg[h] += __shfl_xor(lg[h], 2);
    }
    const int h0 = q * 2;
    s_u[h0 * 128 + z]       = (lg[h0]     + bqkg[(bz0 + z) * 8 + h0])     * 0.125f;
    s_u[(h0 + 1) * 128 + z] = (lg[h0 + 1] + bqkg[(bz0 + z) * 8 + h0 + 1]) * 0.125f;
  }
  __syncthreads();

  // ---------- softmax (head w per wave) -> att in registers ----------
  float att0, att1;
  {
    const float x0 = s_u[w * 128 + L], x1 = s_u[w * 128 + L + 64];
    float mx = fmaxf(x0, x1);
    #pragma unroll
    for (int off = 32; off; off >>= 1) mx = fmaxf(mx, __shfl_xor(mx, off));
    const float e0 = __expf(x0 - mx), e1 = __expf(x1 - mx);
    float sm = e0 + e1;
    #pragma unroll
    for (int off = 32; off; off >>= 1) sm += __shfl_xor(sm, off);
    const float inv = 1.f / sm;
    att0 = e0 * inv; att1 = e1 * inv;
  }

  const int rtf = w & 3, ch2 = w >> 2;          // front roles
  float yv[4] = {0.f, 0.f, 0.f, 0.f};

  #pragma unroll 1
  for (int pass = 0; pass < 2; ++pass){
    const int zp = pass * 64;
    __syncthreads();                                   // protect s_u / s_A reuse

    // ---------- front: hn = LN64(gelu(f @ WveF + bveF)); A-frags in registers ----------
    {
      const int zz = bz0 + zp + rtf * 16 + al;
      const float iv0 = s_qpt[0] - p[zz * 3 + 0];
      const float iv1 = s_qpt[1] - p[zz * 3 + 1];
      const float iv2 = s_qpt[2] - p[zz * 3 + 2];
      bf16x8 fa0, fa1;
      #pragma unroll
      for (int j = 0; j < 8; ++j){
        const int m = g * 8 + j;
        const float pr = TWO_PI_F * (iv0 * Bv[m] + iv1 * Bv[32 + m] + iv2 * Bv[64 + m]);
        float sn, cn; sincosf(pr, &sn, &cn);
        fa0[j] = (short)f2bf(sn);
        fa1[j] = (short)f2bf(cn);
      }
      f32x4 accf[2] = {{0,0,0,0},{0,0,0,0}};
      #pragma unroll
      for (int ct = 0; ct < 2; ++ct){
        const int t = ch2 * 2 + ct;
        const bf16x8 b0 = *(const bf16x8*)(WveFp + ((0 * 4 + t) * 64 + L) * 8);
        const bf16x8 b1 = *(const bf16x8*)(WveFp + ((1 * 4 + t) * 64 + L) * 8);
        accf[ct] = __builtin_amdgcn_mfma_f32_16x16x32_bf16(fa0, b0, accf[ct], 0, 0, 0);
        accf[ct] = __builtin_amdgcn_mfma_f32_16x16x32_bf16(fa1, b1, accf[ct], 0, 0, 0);
      }
      float h1v[2][4];
      #pragma unroll
      for (int r = 0; r < 4; ++r){
        float sv = 0.f, qv = 0.f;
        #pragma unroll
        for (int ct = 0; ct < 2; ++ct){
          const float v = gelu_f(accf[ct][r] + bveF[ch2 * 32 + ct * 16 + al]);
          h1v[ct][r] = v; sv += v; qv += v * v;
        }
        sv += __shfl_xor(sv, 1); sv += __shfl_xor(sv, 2);
        sv += __shfl_xor(sv, 4); sv += __shfl_xor(sv, 8);
        qv += __shfl_xor(qv, 1); qv += __shfl_xor(qv, 2);
        qv += __shfl_xor(qv, 4); qv += __shfl_xor(qv, 8);
        if (al == 0){
          const int row = rtf * 16 + 4 * g + r;
          s_u[row * 4 + ch2 * 2 + 0] = sv;
          s_u[row * 4 + ch2 * 2 + 1] = qv;
        }
      }
      __syncthreads();
      #pragma unroll
      for (int r = 0; r < 4; ++r){
        const int row = rtf * 16 + 4 * g + r;
        const float sv = s_u[row * 4 + 0] + s_u[row * 4 + 2];
        const float qv = s_u[row * 4 + 1] + s_u[row * 4 + 3];
        const float mu = sv * (1.f / 64.f);
        const float rs = rsqrtf(qv * (1.f / 64.f) - mu * mu + EPSF);
        #pragma unroll
        for (int ct = 0; ct < 2; ++ct){
          const int n = ch2 * 32 + ct * 16 + al;
          const float val = (h1v[ct][r] - mu) * rs * vg[n] + vbn[n];
          s_HN[((n >> 5) * 4 + rtf) * 512 + ((4 * g + r) + 16 * ((n >> 3) & 3)) * 8 + (n & 7)] = f2bf(val);
        }
      }
    }
    __syncthreads();

    // ---------- gb MFMA: hn[64x64] @ vW2[64x1024] -> FiLM -> vfilm frags in s_A ----------
    #pragma unroll 1
    for (int ch = 0; ch < 2; ++ch){
      f32x4 accg[2][4], accb[2][4];
      #pragma unroll
      for (int ti = 0; ti < 2; ++ti)
        #pragma unroll
        for (int rt = 0; rt < 4; ++rt){ accg[ti][rt] = (f32x4){0,0,0,0}; accb[ti][rt] = (f32x4){0,0,0,0}; }
      #pragma unroll
      for (int s = 0; s < 2; ++s){
        bf16x8 afr[4];
        #pragma unroll
        for (int rt = 0; rt < 4; ++rt)
          afr[rt] = *(const bf16x8*)(s_HN + ((s * 4 + rt) * 64 + L) * 8);
        #pragma unroll
        for (int ti = 0; ti < 2; ++ti){
          const int tp = w * 4 + ch * 2 + ti;
          const bf16x8 bg = *(const bf16x8*)(vW2p + (size_t)(((s * 32 + tp) * 2 + 0) * 64 + L) * 8);
          const bf16x8 bb = *(const bf16x8*)(vW2p + (size_t)(((s * 32 + tp) * 2 + 1) * 64 + L) * 8);
          #pragma unroll
          for (int rt = 0; rt < 4; ++rt){
            accg[ti][rt] = __builtin_amdgcn_mfma_f32_16x16x32_bf16(afr[rt], bg, accg[ti][rt], 0, 0, 0);
            accb[ti][rt] = __builtin_amdgcn_mfma_f32_16x16x32_bf16(afr[rt], bb, accb[ti][rt], 0, 0, 0);
          }
        }
      }
      #pragma unroll
      for (int ti = 0; ti < 2; ++ti){
        const int n = (w * 4 + ch * 2 + ti) * 16 + al;
        const float gbias = vb2[n], bbias = vb2[512 + n];
        #pragma unroll
        for (int rt = 0; rt < 4; ++rt){
          #pragma unroll
          for (int r = 0; r < 4; ++r){
            const int zl = rt * 16 + 4 * g + r;
            const float v0v = v0g[(size_t)(bz0 + zp + zl) * 512 + n];
            const float vf = v0v * (1.f + accg[ti][rt][r] + gbias) + (accb[ti][rt][r] + bbias);
            s_A[((n >> 5) * 4 + rt) * 512 + ((4 * g + r) + 16 * ((n >> 3) & 3)) * 8 + (n & 7)] = f2bf(vf);
          }
        }
      }
    }
    __syncthreads();

    // ---------- GEMM1: h2 = vfilm @ mW1; gelu + LN512 -> h2n back to s_A ----------
    {
      f32x4 acc[4][4];
      #pragma unroll
      for (int rt = 0; rt < 4; ++rt)
        #pragma unroll
        for (int ct = 0; ct < 4; ++ct) acc[rt][ct] = (f32x4){0,0,0,0};
      gemm_pass(acc, W1p, s_A, w, L);
      #pragma unroll
      for (int rt = 0; rt < 4; ++rt){
        #pragma unroll
        for (int r = 0; r < 4; ++r){
          float sv = 0.f, qv = 0.f;
          #pragma unroll
          for (int ct = 0; ct < 4; ++ct){
            const float v = gelu_f(acc[rt][ct][r] + mb1[w * 64 + ct * 16 + al]);
            acc[rt][ct][r] = v; sv += v; qv += v * v;
          }
          sv += __shfl_xor(sv, 1); sv += __shfl_xor(sv, 2);
          sv += __shfl_xor(sv, 4); sv += __shfl_xor(sv, 8);
          qv += __shfl_xor(qv, 1); qv += __shfl_xor(qv, 2);
          qv += __shfl_xor(qv, 4); qv += __shfl_xor(qv, 8);
          if (al == 0){
            const int zl = rt * 16 + 4 * g + r;
            s_u[zl * 16 + w * 2 + 0] = sv;
            s_u[zl * 16 + w * 2 + 1] = qv;
          }
        }
      }
      __syncthreads();                    // all GEMM1 reads of s_A done + partials visible
      if (tid < 64){
        float sv = 0.f, qv = 0.f;
        #pragma unroll
        for (int ww = 0; ww < 8; ++ww){ sv += s_u[tid * 16 + ww * 2]; qv += s_u[tid * 16 + ww * 2 + 1]; }
        const float mu = sv * (1.f / 512.f);
        s_mu[tid] = mu;
        s_rs[tid] = rsqrtf(qv * (1.f / 512.f) - mu * mu + EPSF);
      }
      __syncthreads();
      #pragma unroll
      for (int rt = 0; rt < 4; ++rt){
        #pragma unroll
        for (int r = 0; r < 4; ++r){
          const int zl = rt * 16 + 4 * g + r;
          const float mu = s_mu[zl], rs = s_rs[zl];
          #pragma unroll
          for (int ct = 0; ct < 4; ++ct){
            const int n = w * 64 + ct * 16 + al;
            const float val = (acc[rt][ct][r] - mu) * rs * mg[n] + mbn[n];
            s_A[((n >> 5) * 4 + rt) * 512 + ((4 * g + r) + 16 * ((n >> 3) & 3)) * 8 + (n & 7)] = f2bf(val);
          }
        }
      }
    }
    __syncthreads();

    // ---------- GEMM2: vfin = h2n @ mW2; y += att * vfin ----------
    {
      f32x4 acc[4][4];
      #pragma unroll
      for (int rt = 0; rt < 4; ++rt)
        #pragma unroll
        for (int ct = 0; ct < 4; ++ct) acc[rt][ct] = (f32x4){0,0,0,0};
      gemm_pass(acc, W2p, s_A, w, L);
      const float attp = pass ? att1 : att0;
      #pragma unroll
      for (int rt = 0; rt < 4; ++rt){
        #pragma unroll
        for (int r = 0; r < 4; ++r){
          const int zl = rt * 16 + 4 * g + r;
          const float aw = __shfl(attp, zl);
          #pragma unroll
          for (int ct = 0; ct < 4; ++ct) yv[ct] += aw * acc[rt][ct][r];
        }
      }
    }
  }

  // ---------- y reduce + write (wave w owns head w's cols) ----------
  #pragma unroll
  for (int ct = 0; ct < 4; ++ct){
    yv[ct] += __shfl_xor(yv[ct], 16);
    yv[ct] += __shfl_xor(yv[ct], 32);
  }
  if (g == 0){
    #pragma unroll
    for (int ct = 0; ct < 4; ++ct){
      const int n = w * 64 + ct * 16 + al;
      yout[(size_t)bc * 512 + n] = yv[ct] + mb2[n];
    }
  }
}

// ---------------- K5: out = y @ Wo + bo (f32) ----------------
__global__ __launch_bounds__(256) void eca_out(
    const float* __restrict__ y, const float* __restrict__ Wo, const float* __restrict__ bo,
    float* __restrict__ out)
{
  const int rt = blockIdx.x >> 2, ct = blockIdx.x & 3;    // 32 row-tiles x 4 col-tiles
  const int tid = threadIdx.x;
  __shared__ float s_y[16][512];
  const float* yb = y + (size_t)rt * 16 * 512;
  for (int i = tid; i < 16 * 128; i += 256)
    ((float4*)&s_y[0][0])[i] = ((const float4*)yb)[i];
  __syncthreads();
  const int jc = ct * 128 + (tid & 31) * 4;
  const int r0 = (tid >> 5) * 2;
  float acc[2][4] = {};
  #pragma unroll 4
  for (int k = 0; k < 512; ++k){
    const float4 wv = *(const float4*)(Wo + (size_t)k * 512 + jc);
    #pragma unroll
    for (int r = 0; r < 2; ++r){
      const float yvv = s_y[r0 + r][k];
      acc[r][0] += yvv * wv.x; acc[r][1] += yvv * wv.y;
      acc[r][2] += yvv * wv.z; acc[r][3] += yvv * wv.w;
    }
  }
  const float4 bv4 = *(const float4*)(bo + jc);
  #pragma unroll
  for (int r = 0; r < 2; ++r){
    float4 o;
    o.x = acc[r][0] + bv4.x; o.y = acc[r][1] + bv4.y;
    o.z = acc[r][2] + bv4.z; o.w = acc[r][3] + bv4.w;
    *(float4*)(out + (size_t)(rt * 16 + r0 + r) * 512 + jc) = o;
  }
}

extern "C" void kernel_launch(void* const* d_in, const int* in_sizes, int n_in,
                              void* d_out, int out_size, void* d_ws, size_t ws_size,
                              hipStream_t stream)
{
  const float* inputs = (const float*)d_in[0];
  const float* p   = (const float*)d_in[1];
  const float* a   = (const float*)d_in[2];
  const float* Bq  = (const float*)d_in[3];
  const float* Wqe = (const float*)d_in[4];
  const float* bqe = (const float*)d_in[5];
  const float* Bv  = (const float*)d_in[6];
  const float* Wve = (const float*)d_in[7];
  const float* bve = (const float*)d_in[8];
  const float* Wq  = (const float*)d_in[9];
  const float* bq  = (const float*)d_in[10];
  const float* Wk  = (const float*)d_in[11];
  const float* bk  = (const float*)d_in[12];
  const float* Wv  = (const float*)d_in[13];
  const float* bv  = (const float*)d_in[14];
  const float* vW1 = (const float*)d_in[15];
  const float* vb1 = (const float*)d_in[16];
  const float* vg  = (const float*)d_in[17];
  const float* vbn = (const float*)d_in[18];
  const float* vW2 = (const float*)d_in[19];
  const float* vb2 = (const float*)d_in[20];
  const float* mW1 = (const float*)d_in[21];
  const float* mb1 = (const float*)d_in[22];
  const float* mg  = (const float*)d_in[23];
  const float* mbn = (const float*)d_in[24];
  const float* mW2 = (const float*)d_in[25];
  const float* mb2 = (const float*)d_in[26];
  const float* Wo  = (const float*)d_in[27];
  const float* bo  = (const float*)d_in[28];
  (void)in_sizes; (void)n_in; (void)out_size; (void)ws_size;

  float* v0g  = (float*)d_ws;                        // 131072 f32
  float* kqf  = v0g + 131072;                        // 131072 f32
  float* bqkg = kqf + 131072;                        // 2048 f32
  float* yws  = bqkg + 2048;                         // 262144 f32
  ushort_t* W1p   = (ushort_t*)(yws + 262144);       // 262144 bf16
  ushort_t* W2p   = W1p + 262144;                    // 262144 bf16
  ushort_t* vW2p  = W2p + 262144;                    // 65536 bf16
  ushort_t* WveFp = vW2p + 65536;                    // 4096 bf16
  float* bveF = (float*)(WveFp + 4096);              // 64 f32
  float* out = (float*)d_out;

  eca_pack<<<dim3(1025), dim3(256), 0, stream>>>(mW1, mW2, vW2, Wve, vW1, bve, vb1,
                                                 W1p, W2p, vW2p, WveFp, bveF);
  eca_prep<<<dim3(NB * NZ), dim3(256), 0, stream>>>(a, Wk, bk, Wv, bv, Wq, bq, Wqe, bqe,
                                                    v0g, kqf, bqkg);
  eca_main<<<dim3(NB * NC), dim3(512), 0, stream>>>(
      inputs, p, Bq, Bv, vg, vbn, vb2, mb1, mg, mbn, mb2,
      v0g, kqf, bqkg, W1p, W2p, vW2p, WveFp, bveF, yws);
  eca_out<<<dim3(128), dim3(256), 0, stream>>>(yws, Wo, bo, out);
}

// Round 7
// 275.019 us; speedup vs baseline: 2.7555x; 1.3187x over previous
//
#include <hip/hip_runtime.h>
#include <hip/hip_bf16.h>
#include <math.h>

#define NB 2
#define NC 256
#define NZ 128
#define NHEADS 8
#define HDIM 64
#define HHID 512
#define EPSF 1e-5f

typedef __attribute__((ext_vector_type(8))) short bf16x8;
typedef __attribute__((ext_vector_type(4))) float f32x4;
typedef unsigned short ushort_t;

__device__ __forceinline__ float gelu_f(float x){
  const float u = 0.7978845608028654f * (x + 0.044715f * x * x * x);
  const float t = 1.0f - 2.0f / (__expf(2.0f * u) + 1.0f);  // tanh(u)
  return 0.5f * x * (1.0f + t);
}

__device__ __forceinline__ ushort_t f2bf(float x){
  unsigned int u = __float_as_uint(x);
  unsigned int r = ((u >> 16) & 1u) + 0x7fffu;   // round-to-nearest-even
  return (ushort_t)((u + r) >> 16);
}

// sin(2*pi*t), cos(2*pi*t): v_sin/v_cos take REVOLUTIONS, fract-reduce first.
__device__ __forceinline__ void fsincos(float t, float* sn, float* cn){
  const float fr = t - floorf(t);
  *sn = __builtin_amdgcn_sinf(fr);
  *cn = __builtin_amdgcn_cosf(fr);
}

// ---------------- K0: pack weights (blocks 0..1024) + per-(b,z) prep (blocks 1025..1280) ----------------
// B-frag: idx=((s*T + t)*64 + L)*8 + j  <->  W[k=s*32+8*(L>>4)+j][n=16*t+(L&15)]
__global__ __launch_bounds__(256) void eca_pre(
    const float* __restrict__ mW1, const float* __restrict__ mW2, const float* __restrict__ vW2,
    const float* __restrict__ Wve, const float* __restrict__ vW1,
    const float* __restrict__ bve, const float* __restrict__ vb1,
    const float* __restrict__ a, const float* __restrict__ Wk, const float* __restrict__ bk,
    const float* __restrict__ Wv, const float* __restrict__ bv,
    const float* __restrict__ Wq, const float* __restrict__ bq,
    const float* __restrict__ Wqe, const float* __restrict__ bqe,
    ushort_t* __restrict__ W1p, ushort_t* __restrict__ W2p, ushort_t* __restrict__ vW2p,
    ushort_t* __restrict__ WveFp, float* __restrict__ bveF,
    float* __restrict__ v0g, float* __restrict__ kqf, float* __restrict__ bqkg)
{
  const int bx = blockIdx.x;
  const int tid = threadIdx.x;
  __shared__ float s_wf[64][64];
  __shared__ float s_a[64];
  __shared__ float s_k[512];
  __shared__ float s_kq[512];

  if (bx < 1024){
    const int i = bx * 256 + tid;
    {
      const int j = i & 7, L = (i >> 3) & 63, t = (i >> 9) & 31, s = i >> 14;
      const int k = s * 32 + ((L >> 4) << 3) + j;
      const int n = (t << 4) + (L & 15);
      W1p[i] = f2bf(mW1[k * 512 + n]);
      W2p[i] = f2bf(mW2[k * 512 + n]);
    }
    if (i < 65536){
      const int j = i & 7, L = (i >> 3) & 63, gb = (i >> 9) & 1, tp = (i >> 10) & 31, s = i >> 15;
      const int k = s * 32 + ((L >> 4) << 3) + j;
      const int n = (tp << 4) + (L & 15) + gb * 512;
      vW2p[i] = f2bf(vW2[k * 1024 + n]);
    }
    return;
  }
  if (bx == 1024){
    // fused front weight: WveF = Wve @ vW1 (64x64), bveF = bve@vW1 + vb1
    const int m = tid >> 2, iq = tid & 3;
    float accv[16];
    #pragma unroll
    for (int ii = 0; ii < 16; ++ii) accv[ii] = 0.f;
    for (int k = 0; k < 64; ++k){
      const float wv = Wve[m * 64 + k];
      const float4* vr = (const float4*)(vW1 + k * 64 + iq * 16);
      float t4[16];
      *(float4*)&t4[0] = vr[0]; *(float4*)&t4[4] = vr[1];
      *(float4*)&t4[8] = vr[2]; *(float4*)&t4[12] = vr[3];
      #pragma unroll
      for (int ii = 0; ii < 16; ++ii) accv[ii] += wv * t4[ii];
    }
    #pragma unroll
    for (int ii = 0; ii < 16; ++ii) s_wf[m][iq * 16 + ii] = accv[ii];
    if (tid < 64){
      float acc = vb1[tid];
      for (int k = 0; k < 64; ++k) acc += bve[k] * vW1[k * 64 + tid];
      bveF[tid] = acc;
    }
    __syncthreads();
    for (int e = tid; e < 4096; e += 256){
      const int j = e & 7, L = (e >> 3) & 63, t = (e >> 9) & 3, s = e >> 11;
      const int k = s * 32 + ((L >> 4) << 3) + j;
      const int n = (t << 4) + (L & 15);
      WveFp[e] = f2bf(s_wf[k][n]);
    }
    return;
  }

  // ---- prep: bz = bx - 1025 ----
  const int bz = bx - 1025;
  if (tid < 64) s_a[tid] = a[bz * 64 + tid];
  __syncthreads();
  #pragma unroll
  for (int jo = 0; jo < 2; ++jo){
    const int j = tid + jo * 256;
    float accK = bk[j], accV = bv[j];
    for (int i = 0; i < 64; ++i){
      const float av = s_a[i];
      accK += av * Wk[i * 512 + j];
      accV += av * Wv[i * 512 + j];
    }
    s_k[j] = accK;
    v0g[(size_t)bz * 512 + j] = accV;
  }
  __syncthreads();
  #pragma unroll
  for (int io = 0; io < 2; ++io){
    const int idx = tid + io * 256;
    const int h = idx >> 6, i = idx & 63;
    float acc = 0.f;
    for (int j = 0; j < 64; ++j)
      acc += Wq[i * 512 + h * 64 + j] * s_k[h * 64 + j];
    s_kq[idx] = acc;
  }
  __syncthreads();
  // KqF[m,h]; layout kqf[bz*512 + (m>>4)*128 + h*16 + (m&15)]
  #pragma unroll
  for (int io = 0; io < 2; ++io){
    const int idx = tid + io * 256;
    const int m = idx >> 3, h = idx & 7;
    float acc = 0.f;
    for (int i = 0; i < 64; ++i) acc += Wqe[m * 64 + i] * s_kq[h * 64 + i];
    kqf[(size_t)bz * 512 + (m >> 4) * 128 + h * 16 + (m & 15)] = acc;
  }
  if (tid < 8){
    float acc = 0.f;
    for (int j = 0; j < 64; ++j) acc += bq[tid * 64 + j] * s_k[tid * 64 + j];
    for (int i = 0; i < 64; ++i) acc += bqe[i] * s_kq[tid * 64 + i];
    bqkg[bz * 8 + tid] = acc;
  }
}

// ---------------- K3: fused per-(b,c); slim registers for 2 blocks/CU ----------------
__global__ __launch_bounds__(512, 4) void eca_main(
    const float* __restrict__ inputs, const float* __restrict__ p,
    const float* __restrict__ Bq, const float* __restrict__ Bv,
    const float* __restrict__ vg, const float* __restrict__ vbn,
    const float* __restrict__ vb2,
    const float* __restrict__ mb1, const float* __restrict__ mg, const float* __restrict__ mbn,
    const float* __restrict__ mb2,
    const float* __restrict__ v0g, const float* __restrict__ kqf, const float* __restrict__ bqkg,
    const ushort_t* __restrict__ W1p, const ushort_t* __restrict__ W2p, const ushort_t* __restrict__ vW2p,
    const ushort_t* __restrict__ WveFp, const float* __restrict__ bveF,
    float* __restrict__ yout)
{
  const int bc = blockIdx.x;
  const int b = bc >> 8;
  const int tid = threadIdx.x;
  const int w = tid >> 6, L = tid & 63;
  const int al = L & 15, g = L >> 4;
  const int bz0 = b * NZ;

  __shared__ __align__(16) ushort_t s_A[16 * 4 * 64 * 8];   // 64KB A-frags (64 z x 512)
  __shared__ __align__(16) ushort_t s_HN[2 * 4 * 64 * 8];   // 8KB hn frags (64 z x 64)
  __shared__ float s_u[1024];                                // union: logits[8][128] / ln partials
  __shared__ float s_mu[64], s_rs[64];
  __shared__ float s_qpt[3];

  if (tid < 3) s_qpt[tid] = inputs[bc * 3 + tid];
  __syncthreads();

  // ---------- logits: thread (z = tid>>2, q = tid&3) ----------
  {
    const int z = tid >> 2, q = tid & 3;
    const float iv0 = s_qpt[0] - p[(bz0 + z) * 3 + 0];
    const float iv1 = s_qpt[1] - p[(bz0 + z) * 3 + 1];
    const float iv2 = s_qpt[2] - p[(bz0 + z) * 3 + 2];
    float tr[16];
    #pragma unroll
    for (int mi = 0; mi < 16; ++mi){
      const int mb = (q & 1) * 16 + mi;
      const float d = iv0 * Bq[mb] + iv1 * Bq[32 + mb] + iv2 * Bq[64 + mb];
      float sn, cn; fsincos(d, &sn, &cn);
      tr[mi] = (q < 2) ? sn : cn;
    }
    const float* kfb = kqf + (size_t)(bz0 + z) * 512 + q * 128;
    float lg[8];
    #pragma unroll
    for (int h = 0; h < 8; ++h){
      const float4 k0 = *(const float4*)(kfb + h * 16);
      const float4 k1 = *(const float4*)(kfb + h * 16 + 4);
      const float4 k2 = *(const float4*)(kfb + h * 16 + 8);
      const float4 k3 = *(const float4*)(kfb + h * 16 + 12);
      lg[h] = tr[0]*k0.x + tr[1]*k0.y + tr[2]*k0.z + tr[3]*k0.w
            + tr[4]*k1.x + tr[5]*k1.y + tr[6]*k1.z + tr[7]*k1.w
            + tr[8]*k2.x + tr[9]*k2.y + tr[10]*k2.z + tr[11]*k2.w
            + tr[12]*k3.x + tr[13]*k3.y + tr[14]*k3.z + tr[15]*k3.w;
    }
    #pragma unroll
    for (int h = 0; h < 8; ++h){
      lg[h] += __shfl_xor(lg[h], 1);
      lg[h] += __shfl_xor(lg[h], 2);
    }
    const int h0 = q * 2;
    s_u[h0 * 128 + z]       = (lg[h0]     + bqkg[(bz0 + z) * 8 + h0])     * 0.125f;
    s_u[(h0 + 1) * 128 + z] = (lg[h0 + 1] + bqkg[(bz0 + z) * 8 + h0 + 1]) * 0.125f;
  }
  __syncthreads();

  // ---------- softmax (head w per wave) -> att in registers ----------
  float att0, att1;
  {
    const float x0 = s_u[w * 128 + L], x1 = s_u[w * 128 + L + 64];
    float mx = fmaxf(x0, x1);
    #pragma unroll
    for (int off = 32; off; off >>= 1) mx = fmaxf(mx, __shfl_xor(mx, off));
    const float e0 = __expf(x0 - mx), e1 = __expf(x1 - mx);
    float sm = e0 + e1;
    #pragma unroll
    for (int off = 32; off; off >>= 1) sm += __shfl_xor(sm, off);
    const float inv = 1.f / sm;
    att0 = e0 * inv; att1 = e1 * inv;
  }

  const int rtf = w & 3, ch2 = w >> 2;          // front roles
  float yv[4] = {0.f, 0.f, 0.f, 0.f};

  #pragma unroll 1
  for (int pass = 0; pass < 2; ++pass){
    const int zp = pass * 64;
    __syncthreads();                                   // protect s_u / s_A reuse

    // ---------- front: hn = LN64(gelu(f @ WveF + bveF)) ----------
    {
      const int zz = bz0 + zp + rtf * 16 + al;
      const float iv0 = s_qpt[0] - p[zz * 3 + 0];
      const float iv1 = s_qpt[1] - p[zz * 3 + 1];
      const float iv2 = s_qpt[2] - p[zz * 3 + 2];
      bf16x8 fa0, fa1;
      #pragma unroll
      for (int j = 0; j < 8; ++j){
        const int m = g * 8 + j;
        const float d = iv0 * Bv[m] + iv1 * Bv[32 + m] + iv2 * Bv[64 + m];
        float sn, cn; fsincos(d, &sn, &cn);
        fa0[j] = (short)f2bf(sn);
        fa1[j] = (short)f2bf(cn);
      }
      f32x4 accf[2] = {{0,0,0,0},{0,0,0,0}};
      #pragma unroll
      for (int ct = 0; ct < 2; ++ct){
        const int t = ch2 * 2 + ct;
        const bf16x8 b0 = *(const bf16x8*)(WveFp + ((0 * 4 + t) * 64 + L) * 8);
        const bf16x8 b1 = *(const bf16x8*)(WveFp + ((1 * 4 + t) * 64 + L) * 8);
        accf[ct] = __builtin_amdgcn_mfma_f32_16x16x32_bf16(fa0, b0, accf[ct], 0, 0, 0);
        accf[ct] = __builtin_amdgcn_mfma_f32_16x16x32_bf16(fa1, b1, accf[ct], 0, 0, 0);
      }
      float h1v[2][4];
      #pragma unroll
      for (int r = 0; r < 4; ++r){
        float sv = 0.f, qv = 0.f;
        #pragma unroll
        for (int ct = 0; ct < 2; ++ct){
          const float v = gelu_f(accf[ct][r] + bveF[ch2 * 32 + ct * 16 + al]);
          h1v[ct][r] = v; sv += v; qv += v * v;
        }
        sv += __shfl_xor(sv, 1); sv += __shfl_xor(sv, 2);
        sv += __shfl_xor(sv, 4); sv += __shfl_xor(sv, 8);
        qv += __shfl_xor(qv, 1); qv += __shfl_xor(qv, 2);
        qv += __shfl_xor(qv, 4); qv += __shfl_xor(qv, 8);
        if (al == 0){
          const int row = rtf * 16 + 4 * g + r;
          s_u[row * 4 + ch2 * 2 + 0] = sv;
          s_u[row * 4 + ch2 * 2 + 1] = qv;
        }
      }
      __syncthreads();
      #pragma unroll
      for (int r = 0; r < 4; ++r){
        const int row = rtf * 16 + 4 * g + r;
        const float sv = s_u[row * 4 + 0] + s_u[row * 4 + 2];
        const float qv = s_u[row * 4 + 1] + s_u[row * 4 + 3];
        const float mu = sv * (1.f / 64.f);
        const float rs = rsqrtf(qv * (1.f / 64.f) - mu * mu + EPSF);
        #pragma unroll
        for (int ct = 0; ct < 2; ++ct){
          const int n = ch2 * 32 + ct * 16 + al;
          const float val = (h1v[ct][r] - mu) * rs * vg[n] + vbn[n];
          s_HN[((n >> 5) * 4 + rtf) * 512 + ((4 * g + r) + 16 * ((n >> 3) & 3)) * 8 + (n & 7)] = f2bf(val);
        }
      }
    }
    __syncthreads();

    // ---------- gb MFMA: one col-tile per iteration (acc = 32 f32) ----------
    #pragma unroll 1
    for (int it = 0; it < 4; ++it){
      f32x4 accg[4], accb[4];
      #pragma unroll
      for (int rt = 0; rt < 4; ++rt){ accg[rt] = (f32x4){0,0,0,0}; accb[rt] = (f32x4){0,0,0,0}; }
      #pragma unroll
      for (int s = 0; s < 2; ++s){
        const int tp = w * 4 + it;
        const bf16x8 bg = *(const bf16x8*)(vW2p + (size_t)(((s * 32 + tp) * 2 + 0) * 64 + L) * 8);
        const bf16x8 bb = *(const bf16x8*)(vW2p + (size_t)(((s * 32 + tp) * 2 + 1) * 64 + L) * 8);
        #pragma unroll
        for (int rt = 0; rt < 4; ++rt){
          const bf16x8 af = *(const bf16x8*)(s_HN + ((s * 4 + rt) * 64 + L) * 8);
          accg[rt] = __builtin_amdgcn_mfma_f32_16x16x32_bf16(af, bg, accg[rt], 0, 0, 0);
          accb[rt] = __builtin_amdgcn_mfma_f32_16x16x32_bf16(af, bb, accb[rt], 0, 0, 0);
        }
      }
      const int n = (w * 4 + it) * 16 + al;
      const float gbias = vb2[n], bbias = vb2[512 + n];
      #pragma unroll
      for (int rt = 0; rt < 4; ++rt){
        #pragma unroll
        for (int r = 0; r < 4; ++r){
          const int zl = rt * 16 + 4 * g + r;
          const float v0v = v0g[(size_t)(bz0 + zp + zl) * 512 + n];
          const float vf = v0v * (1.f + accg[rt][r] + gbias) + (accb[rt][r] + bbias);
          s_A[((n >> 5) * 4 + rt) * 512 + ((4 * g + r) + 16 * ((n >> 3) & 3)) * 8 + (n & 7)] = f2bf(vf);
        }
      }
    }
    __syncthreads();

    // ---------- GEMM1: two 32-z row chunks (acc = 32 f32); gelu + LN512 -> h2n ----------
    #pragma unroll 1
    for (int rc = 0; rc < 2; ++rc){
      f32x4 acc[2][4];
      #pragma unroll
      for (int i = 0; i < 2; ++i)
        #pragma unroll
        for (int ct = 0; ct < 4; ++ct) acc[i][ct] = (f32x4){0,0,0,0};
      {
        bf16x8 b0[4], b1[4];
        #pragma unroll
        for (int ct = 0; ct < 4; ++ct)
          b0[ct] = *(const bf16x8*)(W1p + (size_t)((w * 4 + ct) * 64 + L) * 8);
        #pragma unroll 1
        for (int s2 = 0; s2 < 8; ++s2){
          const int s = 2 * s2;
          #pragma unroll
          for (int ct = 0; ct < 4; ++ct)
            b1[ct] = *(const bf16x8*)(W1p + (size_t)(((s + 1) * 32 + w * 4 + ct) * 64 + L) * 8);
          {
            const bf16x8 a0 = *(const bf16x8*)(s_A + ((s * 4 + rc * 2 + 0) * 64 + L) * 8);
            const bf16x8 a1 = *(const bf16x8*)(s_A + ((s * 4 + rc * 2 + 1) * 64 + L) * 8);
            #pragma unroll
            for (int ct = 0; ct < 4; ++ct){
              acc[0][ct] = __builtin_amdgcn_mfma_f32_16x16x32_bf16(a0, b0[ct], acc[0][ct], 0, 0, 0);
              acc[1][ct] = __builtin_amdgcn_mfma_f32_16x16x32_bf16(a1, b0[ct], acc[1][ct], 0, 0, 0);
            }
          }
          const int sn = (s2 < 7) ? (s + 2) : 0;
          #pragma unroll
          for (int ct = 0; ct < 4; ++ct)
            b0[ct] = *(const bf16x8*)(W1p + (size_t)((sn * 32 + w * 4 + ct) * 64 + L) * 8);
          {
            const bf16x8 a0 = *(const bf16x8*)(s_A + (((s + 1) * 4 + rc * 2 + 0) * 64 + L) * 8);
            const bf16x8 a1 = *(const bf16x8*)(s_A + (((s + 1) * 4 + rc * 2 + 1) * 64 + L) * 8);
            #pragma unroll
            for (int ct = 0; ct < 4; ++ct){
              acc[0][ct] = __builtin_amdgcn_mfma_f32_16x16x32_bf16(a0, b1[ct], acc[0][ct], 0, 0, 0);
              acc[1][ct] = __builtin_amdgcn_mfma_f32_16x16x32_bf16(a1, b1[ct], acc[1][ct], 0, 0, 0);
            }
          }
        }
      }
      // epilogue: gelu + row partials
      #pragma unroll
      for (int i = 0; i < 2; ++i){
        #pragma unroll
        for (int r = 0; r < 4; ++r){
          float sv = 0.f, qv = 0.f;
          #pragma unroll
          for (int ct = 0; ct < 4; ++ct){
            const float v = gelu_f(acc[i][ct][r] + mb1[w * 64 + ct * 16 + al]);
            acc[i][ct][r] = v; sv += v; qv += v * v;
          }
          sv += __shfl_xor(sv, 1); sv += __shfl_xor(sv, 2);
          sv += __shfl_xor(sv, 4); sv += __shfl_xor(sv, 8);
          qv += __shfl_xor(qv, 1); qv += __shfl_xor(qv, 2);
          qv += __shfl_xor(qv, 4); qv += __shfl_xor(qv, 8);
          if (al == 0){
            const int zl = rc * 32 + i * 16 + 4 * g + r;
            s_u[zl * 16 + w * 2 + 0] = sv;
            s_u[zl * 16 + w * 2 + 1] = qv;
          }
        }
      }
      __syncthreads();
      if (tid < 32){
        const int zl = rc * 32 + tid;
        float sv = 0.f, qv = 0.f;
        #pragma unroll
        for (int ww = 0; ww < 8; ++ww){ sv += s_u[zl * 16 + ww * 2]; qv += s_u[zl * 16 + ww * 2 + 1]; }
        const float mu = sv * (1.f / 512.f);
        s_mu[zl] = mu;
        s_rs[zl] = rsqrtf(qv * (1.f / 512.f) - mu * mu + EPSF);
      }
      __syncthreads();
      #pragma unroll
      for (int i = 0; i < 2; ++i){
        #pragma unroll
        for (int r = 0; r < 4; ++r){
          const int zl = rc * 32 + i * 16 + 4 * g + r;
          const float mu = s_mu[zl], rs = s_rs[zl];
          #pragma unroll
          for (int ct = 0; ct < 4; ++ct){
            const int n = w * 64 + ct * 16 + al;
            const float val = (acc[i][ct][r] - mu) * rs * mg[n] + mbn[n];
            s_A[((n >> 5) * 4 + rc * 2 + i) * 512 + ((4 * g + r) + 16 * ((n >> 3) & 3)) * 8 + (n & 7)] = f2bf(val);
          }
        }
      }
    }
    __syncthreads();                      // all h2n visible before GEMM2 reads

    // ---------- GEMM2: two 32-z row chunks; y += att * vfin ----------
    const float attp = pass ? att1 : att0;
    #pragma unroll 1
    for (int rc = 0; rc < 2; ++rc){
      f32x4 acc[2][4];
      #pragma unroll
      for (int i = 0; i < 2; ++i)
        #pragma unroll
        for (int ct = 0; ct < 4; ++ct) acc[i][ct] = (f32x4){0,0,0,0};
      {
        bf16x8 b0[4], b1[4];
        #pragma unroll
        for (int ct = 0; ct < 4; ++ct)
          b0[ct] = *(const bf16x8*)(W2p + (size_t)((w * 4 + ct) * 64 + L) * 8);
        #pragma unroll 1
        for (int s2 = 0; s2 < 8; ++s2){
          const int s = 2 * s2;
          #pragma unroll
          for (int ct = 0; ct < 4; ++ct)
            b1[ct] = *(const bf16x8*)(W2p + (size_t)(((s + 1) * 32 + w * 4 + ct) * 64 + L) * 8);
          {
            const bf16x8 a0 = *(const bf16x8*)(s_A + ((s * 4 + rc * 2 + 0) * 64 + L) * 8);
            const bf16x8 a1 = *(const bf16x8*)(s_A + ((s * 4 + rc * 2 + 1) * 64 + L) * 8);
            #pragma unroll
            for (int ct = 0; ct < 4; ++ct){
              acc[0][ct] = __builtin_amdgcn_mfma_f32_16x16x32_bf16(a0, b0[ct], acc[0][ct], 0, 0, 0);
              acc[1][ct] = __builtin_amdgcn_mfma_f32_16x16x32_bf16(a1, b0[ct], acc[1][ct], 0, 0, 0);
            }
          }
          const int sn = (s2 < 7) ? (s + 2) : 0;
          #pragma unroll
          for (int ct = 0; ct < 4; ++ct)
            b0[ct] = *(const bf16x8*)(W2p + (size_t)((sn * 32 + w * 4 + ct) * 64 + L) * 8);
          {
            const bf16x8 a0 = *(const bf16x8*)(s_A + (((s + 1) * 4 + rc * 2 + 0) * 64 + L) * 8);
            const bf16x8 a1 = *(const bf16x8*)(s_A + (((s + 1) * 4 + rc * 2 + 1) * 64 + L) * 8);
            #pragma unroll
            for (int ct = 0; ct < 4; ++ct){
              acc[0][ct] = __builtin_amdgcn_mfma_f32_16x16x32_bf16(a0, b1[ct], acc[0][ct], 0, 0, 0);
              acc[1][ct] = __builtin_amdgcn_mfma_f32_16x16x32_bf16(a1, b1[ct], acc[1][ct], 0, 0, 0);
            }
          }
        }
      }
      #pragma unroll
      for (int i = 0; i < 2; ++i){
        #pragma unroll
        for (int r = 0; r < 4; ++r){
          const int zl = rc * 32 + i * 16 + 4 * g + r;
          const float aw = __shfl(attp, zl);
          #pragma unroll
          for (int ct = 0; ct < 4; ++ct) yv[ct] += aw * acc[i][ct][r];
        }
      }
    }
  }

  // ---------- y reduce + write (wave w owns head w's cols) ----------
  #pragma unroll
  for (int ct = 0; ct < 4; ++ct){
    yv[ct] += __shfl_xor(yv[ct], 16);
    yv[ct] += __shfl_xor(yv[ct], 32);
  }
  if (g == 0){
    #pragma unroll
    for (int ct = 0; ct < 4; ++ct){
      const int n = w * 64 + ct * 16 + al;
      yout[(size_t)bc * 512 + n] = yv[ct] + mb2[n];
    }
  }
}

// ---------------- K5: out = y @ Wo + bo (f32) ----------------
__global__ __launch_bounds__(256) void eca_out(
    const float* __restrict__ y, const float* __restrict__ Wo, const float* __restrict__ bo,
    float* __restrict__ out)
{
  const int rt = blockIdx.x >> 2, ct = blockIdx.x & 3;    // 32 row-tiles x 4 col-tiles
  const int tid = threadIdx.x;
  __shared__ float s_y[16][512];
  const float* yb = y + (size_t)rt * 16 * 512;
  for (int i = tid; i < 16 * 128; i += 256)
    ((float4*)&s_y[0][0])[i] = ((const float4*)yb)[i];
  __syncthreads();
  const int jc = ct * 128 + (tid & 31) * 4;
  const int r0 = (tid >> 5) * 2;
  float acc[2][4] = {};
  #pragma unroll 4
  for (int k = 0; k < 512; ++k){
    const float4 wv = *(const float4*)(Wo + (size_t)k * 512 + jc);
    #pragma unroll
    for (int r = 0; r < 2; ++r){
      const float yvv = s_y[r0 + r][k];
      acc[r][0] += yvv * wv.x; acc[r][1] += yvv * wv.y;
      acc[r][2] += yvv * wv.z; acc[r][3] += yvv * wv.w;
    }
  }
  const float4 bv4 = *(const float4*)(bo + jc);
  #pragma unroll
  for (int r = 0; r < 2; ++r){
    float4 o;
    o.x = acc[r][0] + bv4.x; o.y = acc[r][1] + bv4.y;
    o.z = acc[r][2] + bv4.z; o.w = acc[r][3] + bv4.w;
    *(float4*)(out + (size_t)(rt * 16 + r0 + r) * 512 + jc) = o;
  }
}

extern "C" void kernel_launch(void* const* d_in, const int* in_sizes, int n_in,
                              void* d_out, int out_size, void* d_ws, size_t ws_size,
                              hipStream_t stream)
{
  const float* inputs = (const float*)d_in[0];
  const float* p   = (const float*)d_in[1];
  const float* a   = (const float*)d_in[2];
  const float* Bq  = (const float*)d_in[3];
  const float* Wqe = (const float*)d_in[4];
  const float* bqe = (const float*)d_in[5];
  const float* Bv  = (const float*)d_in[6];
  const float* Wve = (const float*)d_in[7];
  const float* bve = (const float*)d_in[8];
  const float* Wq  = (const float*)d_in[9];
  const float* bq  = (const float*)d_in[10];
  const float* Wk  = (const float*)d_in[11];
  const float* bk  = (const float*)d_in[12];
  const float* Wv  = (const float*)d_in[13];
  const float* bv  = (const float*)d_in[14];
  const float* vW1 = (const float*)d_in[15];
  const float* vb1 = (const float*)d_in[16];
  const float* vg  = (const float*)d_in[17];
  const float* vbn = (const float*)d_in[18];
  const float* vW2 = (const float*)d_in[19];
  const float* vb2 = (const float*)d_in[20];
  const float* mW1 = (const float*)d_in[21];
  const float* mb1 = (const float*)d_in[22];
  const float* mg  = (const float*)d_in[23];
  const float* mbn = (const float*)d_in[24];
  const float* mW2 = (const float*)d_in[25];
  const float* mb2 = (const float*)d_in[26];
  const float* Wo  = (const float*)d_in[27];
  const float* bo  = (const float*)d_in[28];
  (void)in_sizes; (void)n_in; (void)out_size; (void)ws_size;

  float* v0g  = (float*)d_ws;                        // 131072 f32
  float* kqf  = v0g + 131072;                        // 131072 f32
  float* bqkg = kqf + 131072;                        // 2048 f32
  float* yws  = bqkg + 2048;                         // 262144 f32
  ushort_t* W1p   = (ushort_t*)(yws + 262144);       // 262144 bf16
  ushort_t* W2p   = W1p + 262144;                    // 262144 bf16
  ushort_t* vW2p  = W2p + 262144;                    // 65536 bf16
  ushort_t* WveFp = vW2p + 65536;                    // 4096 bf16
  float* bveF = (float*)(WveFp + 4096);              // 64 f32
  float* out = (float*)d_out;

  eca_pre<<<dim3(1281), dim3(256), 0, stream>>>(
      mW1, mW2, vW2, Wve, vW1, bve, vb1,
      a, Wk, bk, Wv, bv, Wq, bq, Wqe, bqe,
      W1p, W2p, vW2p, WveFp, bveF, v0g, kqf, bqkg);
  eca_main<<<dim3(NB * NC), dim3(512), 0, stream>>>(
      inputs, p, Bq, Bv, vg, vbn, vb2, mb1, mg, mbn, mb2,
      v0g, kqf, bqkg, W1p, W2p, vW2p, WveFp, bveF, yws);
  eca_out<<<dim3(128), dim3(256), 0, stream>>>(yws, Wo, bo, out);
}